// Round 12
// baseline (12390.937 us; speedup 1.0000x reference)
//
#include <hip/hip_runtime.h>
#include <hip/hip_bf16.h>
#include <hip/hip_cooperative_groups.h>

namespace cg = cooperative_groups;

#define SORB  64
#define HID   512
#define BATCH 4096
#define N3H   1536
#define KD    512
#define BK    64
#define PI_F  3.14159265358979f

typedef _Float16 half8 __attribute__((ext_vector_type(8)));
typedef float    floatx4 __attribute__((ext_vector_type(4)));

__device__ __forceinline__ void gload16(const void* g, void* l) {
    __builtin_amdgcn_global_load_lds(
        (const __attribute__((address_space(1))) void*)g,
        (__attribute__((address_space(3))) void*)l, 16, 0, 0);
}

__device__ __forceinline__ float sigmoidf_(float x) { return 1.f / (1.f + __expf(-x)); }
__device__ __forceinline__ float tanhf_(float x) {
    x = fminf(fmaxf(x, -15.f), 15.f);
    const float e2 = __expf(2.f * x);
    return (e2 - 1.f) / (e2 + 1.f);
}

__global__ __launch_bounds__(256) void convw_kernel(
    const float* __restrict__ w0, const float* __restrict__ w1, const float* __restrict__ w2,
    _Float16* __restrict__ o0, _Float16* __restrict__ o1, _Float16* __restrict__ o2)
{
    const int i = blockIdx.x * 256 + threadIdx.x;
    if (i < N3H * KD) {
        o0[i] = (_Float16)w0[i];
        o1[i] = (_Float16)w1[i];
        o2[i] = (_Float16)w2[i];
    }
}

__global__ __launch_bounds__(256) void init_kernel(
    float* __restrict__ amp, float* __restrict__ phase,
    int* __restrict__ nup, int* __restrict__ ndn)
{
    const int i = blockIdx.x * 256 + threadIdx.x;
    if (i < BATCH) { amp[i] = 1.f; phase[i] = 0.f; nup[i] = 0; ndn[i] = 0; }
}

// heads + per-row accumulation for `step`; writes `out` only when step==63.
__device__ __forceinline__ void do_head(
    const _Float16* __restrict__ h1, 
    const float* __restrict__ Wamp, const float* __restrict__ bamp,
    const float* __restrict__ Wph,  const float* __restrict__ bph,
    const int* __restrict__ bits,
    float* __restrict__ amp, float* __restrict__ phase,
    int* __restrict__ nup, int* __restrict__ ndn,
    float* __restrict__ out, int step, int nb, int lane, int wid)
{
    for (int m = blockIdx.x * 4 + wid; m < BATCH; m += nb * 4) {
        const half8 hv = *(const half8*)(h1 + (size_t)m * HID + lane * 8);
        float d0 = 0.f, d1 = 0.f, d2 = 0.f, d3 = 0.f;
#pragma unroll
        for (int e = 0; e < 8; ++e) {
            const int j = lane * 8 + e;
            const float hn = (float)hv[e];
            d0 += hn * Wamp[j];       d1 += hn * Wamp[HID + j];
            d2 += hn * Wph[j];        d3 += hn * Wph[HID + j];
        }
#pragma unroll
        for (int off = 1; off < 64; off <<= 1) {
            d0 += __shfl_xor(d0, off); d1 += __shfl_xor(d1, off);
            d2 += __shfl_xor(d2, off); d3 += __shfl_xor(d3, off);
        }
        if (lane == 0) {
            const float a0 = d0 + bamp[0];
            const float a1 = d1 + bamp[1];
            const float mx = fmaxf(a0, a1);
            const float e0 = __expf(a0 - mx), e1 = __expf(a1 - mx);
            const float inv = 1.f / (e0 + e1);
            float ya0 = sqrtf(e0 * inv), ya1 = sqrtf(e1 * inv);
            const float p0 = d2 + bph[0];
            const float p1 = d3 + bph[1];
            const float yp0 = PI_F * p0 / (1.f + fabsf(p0));
            const float yp1 = PI_F * p1 / (1.f + fabsf(p1));
            const int even = ((step & 1) == 0);
            const int cnt = even ? nup[m] : ndn[m];
            if (step >= 32) {  // MIN_I
                const int lower = (step >> 1) - 16;
                const float m0v = (cnt > lower) ? ya0 : 0.f;
                const float m1v = (cnt < 16) ? ya1 : 0.f;
                const float nrm = sqrtf(m0v * m0v + m1v * m1v + 1e-12f);
                ya0 = m0v / nrm; ya1 = m1v / nrm;
            }
            const int bi = bits[m * SORB + step];
            const float na = amp[m] * (bi ? ya1 : ya0);
            const float np = phase[m] + (bi ? yp1 : yp0);
            amp[m] = na; phase[m] = np;
            if (bi) { if (even) nup[m] = cnt + 1; else ndn[m] = cnt + 1; }
            if (step == SORB - 1) {
                out[m * 2 + 0] = na;
                out[m * 2 + 1] = np;
            }
        }
    }
}

// ================= persistent cooperative scan kernel =================
// per step: {head(s-1), phase1: 1024 tiles (z0: gh0+gates0, z1: gh1->gB)}
//           grid.sync()  {phase2: 1024 BM=32 tiles gi1+gates1}  grid.sync()
__global__ __launch_bounds__(256, 4) void fused_kernel(
    _Float16* __restrict__ h0hA, _Float16* __restrict__ h0hB,
    _Float16* __restrict__ h1hA, _Float16* __restrict__ h1hB,
    const _Float16* __restrict__ wh0, const _Float16* __restrict__ wi1,
    const _Float16* __restrict__ wh1,
    const float* __restrict__ Wih0, const int* __restrict__ bits,
    float* __restrict__ h0f, float* __restrict__ h1f, _Float16* __restrict__ gB,
    const float* __restrict__ Wamp, const float* __restrict__ bamp,
    const float* __restrict__ Wph,  const float* __restrict__ bph,
    float* __restrict__ amp, float* __restrict__ phase,
    int* __restrict__ nup, int* __restrict__ ndn, float* __restrict__ out)
{
    cg::grid_group gg = cg::this_grid();
    __shared__ __align__(16) _Float16 smem[256 * BK];   // 32 KB
    _Float16* As = smem;              // 64 rows (phase1) / 32 rows (phase2)
    _Float16* Bs = smem + 64 * BK;    // 192 rows

    const int tid  = threadIdx.x;
    const int lane = tid & 63;
    const int wid  = tid >> 6;
    const int wm   = wid >> 1, wj = wid & 1;
    const int ku   = lane >> 4;
    const int nb   = gridDim.x;

    // tile-local fragment offsets (independent of j0/m0)
    int aoff1[2][2];                 // phase1 A (BM=64)
#pragma unroll
    for (int mf = 0; mf < 2; ++mf) {
        const int r = wm * 32 + mf * 16 + (lane & 15);
#pragma unroll
        for (int kk = 0; kk < 2; ++kk)
            aoff1[mf][kk] = r * BK + (((kk * 4 + ku) ^ (r & 7)) * 8);
    }
    int aoff2[2];                    // phase2 A (BM=32)
    {
        const int r = wm * 16 + (lane & 15);
#pragma unroll
        for (int kk = 0; kk < 2; ++kk)
            aoff2[kk] = r * BK + (((kk * 4 + ku) ^ (r & 7)) * 8);
    }
    int boff[2][3][2];               // B (192 rows, both phases)
#pragma unroll
    for (int jf = 0; jf < 2; ++jf)
#pragma unroll
        for (int g = 0; g < 3; ++g) {
            const int r = g * 64 + wj * 32 + jf * 16 + (lane & 15);
#pragma unroll
            for (int kk = 0; kk < 2; ++kk)
                boff[jf][g][kk] = r * BK + (((kk * 4 + ku) ^ (r & 7)) * 8);
        }
    // LDS staging dests (wave-uniform)
    _Float16* a_dst[2];
#pragma unroll
    for (int k2 = 0; k2 < 2; ++k2) a_dst[k2] = As + (size_t)(k2 * 256 + wid * 64) * 8;
    _Float16* b_dst[6];
#pragma unroll
    for (int k2 = 0; k2 < 6; ++k2) b_dst[k2] = Bs + (size_t)(k2 * 256 + wid * 64) * 8;

#pragma unroll 1
    for (int s = 0; s < SORB; ++s) {
        _Float16* h0c = (s & 1) ? h0hB : h0hA;
        _Float16* h0n = (s & 1) ? h0hA : h0hB;
        _Float16* h1c = (s & 1) ? h1hB : h1hA;
        _Float16* h1n = (s & 1) ? h1hA : h1hB;

        if (s > 0)
            do_head(h1c, Wamp, bamp, Wph, bph, bits, amp, phase, nup, ndn,
                    out, s - 1, nb, lane, wid);

        // -------- phase 1: 1024 tiles --------
        for (int t = blockIdx.x; t < 1024; t += nb) {
            const int z  = t >> 9;
            const int j0 = (t & 7) * 64;
            const int m0 = ((t >> 3) & 63) * 64;
            const _Float16* Aop = z ? h1c : h0c;
            const _Float16* Wop = z ? wh1 : wh0;

            floatx4 acc[2][2][3];
            const floatx4 z4 = {0.f, 0.f, 0.f, 0.f};
#pragma unroll
            for (int a = 0; a < 2; ++a)
#pragma unroll
                for (int b = 0; b < 2; ++b)
#pragma unroll
                    for (int g = 0; g < 3; ++g) acc[a][b][g] = z4;

            const _Float16* a_srcp[2];
#pragma unroll
            for (int k2 = 0; k2 < 2; ++k2) {
                const int p = tid + k2 * 256, row = p >> 3, c = (p & 7) ^ (row & 7);
                a_srcp[k2] = Aop + (size_t)(m0 + row) * KD + c * 8;
            }
            const _Float16* b_srcp[6];
#pragma unroll
            for (int k2 = 0; k2 < 6; ++k2) {
                const int p = tid + k2 * 256, row = p >> 3, c = (p & 7) ^ (row & 7);
                const int grow = (row >> 6) * HID + j0 + (row & 63);
                b_srcp[k2] = Wop + (size_t)grow * KD + c * 8;
            }

            for (int kt = 0; kt < 8; ++kt) {
                const int k0 = kt * BK;
#pragma unroll
                for (int k2 = 0; k2 < 2; ++k2) gload16(a_srcp[k2] + k0, a_dst[k2]);
#pragma unroll
                for (int k2 = 0; k2 < 6; ++k2) gload16(b_srcp[k2] + k0, b_dst[k2]);
                __syncthreads();
#pragma unroll
                for (int kk = 0; kk < 2; ++kk) {
                    half8 af[2], bf[2][3];
#pragma unroll
                    for (int mf = 0; mf < 2; ++mf) af[mf] = *(const half8*)(As + aoff1[mf][kk]);
#pragma unroll
                    for (int jf = 0; jf < 2; ++jf)
#pragma unroll
                        for (int g = 0; g < 3; ++g) bf[jf][g] = *(const half8*)(Bs + boff[jf][g][kk]);
#pragma unroll
                    for (int mf = 0; mf < 2; ++mf)
#pragma unroll
                        for (int jf = 0; jf < 2; ++jf)
#pragma unroll
                            for (int g = 0; g < 3; ++g)
                                acc[mf][jf][g] = __builtin_amdgcn_mfma_f32_16x16x32_f16(
                                    af[mf], bf[jf][g], acc[mf][jf][g], 0, 0, 0);
                }
                __syncthreads();
            }

            if (z == 0) {
#pragma unroll
                for (int mf = 0; mf < 2; ++mf)
#pragma unroll
                    for (int jf = 0; jf < 2; ++jf) {
                        const floatx4 gr = acc[mf][jf][0];
                        const floatx4 gz = acc[mf][jf][1];
                        const floatx4 gn = acc[mf][jf][2];
#pragma unroll
                        for (int reg = 0; reg < 4; ++reg) {
                            const int m = m0 + wm * 32 + mf * 16 + (lane >> 4) * 4 + reg;
                            const int j = j0 + wj * 32 + jf * 16 + (lane & 15);
                            float gir = 0.f, giz = 0.f, gin = 0.f;
                            if (s > 0) {
                                const int tb = bits[m * SORB + s - 1];
                                gir = Wih0[j * 2 + tb];
                                giz = Wih0[(HID + j) * 2 + tb];
                                gin = Wih0[(2 * HID + j) * 2 + tb];
                            }
                            const float r  = sigmoidf_(gir + gr[reg]);
                            const float zz = sigmoidf_(giz + gz[reg]);
                            const float n  = tanhf_(gin + r * gn[reg]);
                            const size_t idx = (size_t)m * HID + j;
                            const float h  = h0f[idx];
                            const float hn = (1.f - zz) * n + zz * h;
                            h0f[idx] = hn;
                            h0n[idx] = (_Float16)hn;
                        }
                    }
            } else {
#pragma unroll
                for (int mf = 0; mf < 2; ++mf)
#pragma unroll
                    for (int jf = 0; jf < 2; ++jf)
#pragma unroll
                        for (int g = 0; g < 3; ++g)
#pragma unroll
                            for (int reg = 0; reg < 4; ++reg) {
                                const int m = m0 + wm * 32 + mf * 16 + (lane >> 4) * 4 + reg;
                                const int j = j0 + wj * 32 + jf * 16 + (lane & 15);
                                gB[(size_t)m * N3H + g * HID + j] = (_Float16)acc[mf][jf][g][reg];
                            }
            }
        }
        gg.sync();

        // -------- phase 2: 1024 BM=32 tiles --------
        for (int t = blockIdx.x; t < 1024; t += nb) {
            const int j0 = (t & 7) * 64;
            const int m0 = (t >> 3) * 32;

            floatx4 acc2[2][3];
            const floatx4 z4 = {0.f, 0.f, 0.f, 0.f};
#pragma unroll
            for (int b = 0; b < 2; ++b)
#pragma unroll
                for (int g = 0; g < 3; ++g) acc2[b][g] = z4;

            const int p = tid, rowA = p >> 3, cA = (p & 7) ^ (rowA & 7);
            const _Float16* a_src = h0n + (size_t)(m0 + rowA) * KD + cA * 8;
            const _Float16* b_srcp[6];
#pragma unroll
            for (int k2 = 0; k2 < 6; ++k2) {
                const int q = tid + k2 * 256, row = q >> 3, c = (q & 7) ^ (row & 7);
                const int grow = (row >> 6) * HID + j0 + (row & 63);
                b_srcp[k2] = wi1 + (size_t)grow * KD + c * 8;
            }

            for (int kt = 0; kt < 8; ++kt) {
                const int k0 = kt * BK;
                gload16(a_src + k0, a_dst[0]);
#pragma unroll
                for (int k2 = 0; k2 < 6; ++k2) gload16(b_srcp[k2] + k0, b_dst[k2]);
                __syncthreads();
#pragma unroll
                for (int kk = 0; kk < 2; ++kk) {
                    half8 af;
                    af = *(const half8*)(As + aoff2[kk]);
                    half8 bf[2][3];
#pragma unroll
                    for (int jf = 0; jf < 2; ++jf)
#pragma unroll
                        for (int g = 0; g < 3; ++g) bf[jf][g] = *(const half8*)(Bs + boff[jf][g][kk]);
#pragma unroll
                    for (int jf = 0; jf < 2; ++jf)
#pragma unroll
                        for (int g = 0; g < 3; ++g)
                            acc2[jf][g] = __builtin_amdgcn_mfma_f32_16x16x32_f16(
                                af, bf[jf][g], acc2[jf][g], 0, 0, 0);
                }
                __syncthreads();
            }

            // fused gates1
#pragma unroll
            for (int jf = 0; jf < 2; ++jf) {
                const floatx4 gr = acc2[jf][0];
                const floatx4 gz = acc2[jf][1];
                const floatx4 gn = acc2[jf][2];
#pragma unroll
                for (int reg = 0; reg < 4; ++reg) {
                    const int m = m0 + wm * 16 + (lane >> 4) * 4 + reg;
                    const int j = j0 + wj * 32 + jf * 16 + (lane & 15);
                    const size_t gbase = (size_t)m * N3H;
                    const float ghr = (float)gB[gbase + j];
                    const float ghz = (float)gB[gbase + HID + j];
                    const float ghn = (float)gB[gbase + 2 * HID + j];
                    const float r  = sigmoidf_(gr[reg] + ghr);
                    const float zz = sigmoidf_(gz[reg] + ghz);
                    const float n  = tanhf_(gn[reg] + r * ghn);
                    const size_t idx = (size_t)m * HID + j;
                    const float h  = h1f[idx];
                    const float hn = (1.f - zz) * n + zz * h;
                    h1f[idx] = hn;
                    h1n[idx] = (_Float16)hn;
                }
            }
        }
        gg.sync();
    }

    // final head (step 63): h1h[ (63&1)^1 ] = h1hA
    do_head(h1hA, Wamp, bamp, Wph, bph, bits, amp, phase, nup, ndn,
            out, SORB - 1, nb, lane, wid);
}

extern "C" void kernel_launch(void* const* d_in, const int* in_sizes, int n_in,
                              void* d_out, int out_size, void* d_ws, size_t ws_size,
                              hipStream_t stream) {
    const int*   bits = (const int*)d_in[0];
    const float* Wih0 = (const float*)d_in[1];
    const float* Whh0 = (const float*)d_in[2];
    const float* Wih1 = (const float*)d_in[3];
    const float* Whh1 = (const float*)d_in[4];
    const float* Wamp = (const float*)d_in[5];
    const float* bamp = (const float*)d_in[6];
    const float* Wph  = (const float*)d_in[7];
    const float* bph  = (const float*)d_in[8];
    float* out = (float*)d_out;

    char* ws = (char*)d_ws;
    size_t off = 0;
    auto alloc = [&](size_t bytes) {
        void* p = ws + off;
        off = (off + bytes + 255) & ~(size_t)255;
        return p;
    };
    _Float16* wh0 = (_Float16*)alloc((size_t)N3H * KD * 2);
    _Float16* wi1 = (_Float16*)alloc((size_t)N3H * KD * 2);
    _Float16* wh1 = (_Float16*)alloc((size_t)N3H * KD * 2);
    float*    h0f = (float*)alloc((size_t)BATCH * HID * 4);
    float*    h1f = (float*)alloc((size_t)BATCH * HID * 4);
    _Float16* h0hA = (_Float16*)alloc((size_t)BATCH * HID * 2);
    _Float16* h0hB = (_Float16*)alloc((size_t)BATCH * HID * 2);
    _Float16* h1hA = (_Float16*)alloc((size_t)BATCH * HID * 2);
    _Float16* h1hB = (_Float16*)alloc((size_t)BATCH * HID * 2);
    _Float16* gB  = (_Float16*)alloc((size_t)BATCH * N3H * 2);
    float*    amp   = (float*)alloc((size_t)BATCH * 4);
    float*    phase = (float*)alloc((size_t)BATCH * 4);
    int*      nup   = (int*)alloc((size_t)BATCH * 4);
    int*      ndn   = (int*)alloc((size_t)BATCH * 4);

    hipMemsetAsync(h0f, 0, (size_t)BATCH * HID * 4, stream);
    hipMemsetAsync(h1f, 0, (size_t)BATCH * HID * 4, stream);
    hipMemsetAsync(h0hA, 0, (size_t)BATCH * HID * 2, stream);
    hipMemsetAsync(h1hA, 0, (size_t)BATCH * HID * 2, stream);
    convw_kernel<<<(N3H * KD + 255) / 256, 256, 0, stream>>>(Whh0, Wih1, Whh1, wh0, wi1, wh1);
    init_kernel<<<BATCH / 256, 256, 0, stream>>>(amp, phase, nup, ndn);

    int maxb = 0;
    hipOccupancyMaxActiveBlocksPerMultiprocessor(&maxb, fused_kernel, 256, 0);
    int nblocks = maxb * 256;
    if (nblocks > 1024) nblocks = 1024;
    if (nblocks < 256)  nblocks = 256;

    void* kargs[] = {
        (void*)&h0hA, (void*)&h0hB, (void*)&h1hA, (void*)&h1hB,
        (void*)&wh0, (void*)&wi1, (void*)&wh1,
        (void*)&Wih0, (void*)&bits,
        (void*)&h0f, (void*)&h1f, (void*)&gB,
        (void*)&Wamp, (void*)&bamp, (void*)&Wph, (void*)&bph,
        (void*)&amp, (void*)&phase, (void*)&nup, (void*)&ndn, (void*)&out
    };
    hipLaunchCooperativeKernel(fused_kernel, dim3(nblocks), dim3(256), kargs, 0, stream);
}

// Round 13
// 4071.149 us; speedup vs baseline: 3.0436x; 3.0436x over previous
//
#include <hip/hip_runtime.h>
#include <hip/hip_bf16.h>

#define SORB  64
#define HID   512
#define BATCH 4096
#define N3H   1536
#define KD    512
#define BK    64
#define PI_F  3.14159265358979f

typedef _Float16 half8 __attribute__((ext_vector_type(8)));
typedef float    floatx4 __attribute__((ext_vector_type(4)));

__device__ __forceinline__ void gload16(const void* g, void* l) {
    __builtin_amdgcn_global_load_lds(
        (const __attribute__((address_space(1))) void*)g,
        (__attribute__((address_space(3))) void*)l, 16, 0, 0);
}

__device__ __forceinline__ float sigmoidf_(float x) { return 1.f / (1.f + __expf(-x)); }
__device__ __forceinline__ float tanhf_(float x) {
    x = fminf(fmaxf(x, -15.f), 15.f);
    const float e2 = __expf(2.f * x);
    return (e2 - 1.f) / (e2 + 1.f);
}

__global__ __launch_bounds__(256) void convw_kernel(
    const float* __restrict__ w0, const float* __restrict__ w1, const float* __restrict__ w2,
    _Float16* __restrict__ o0, _Float16* __restrict__ o1, _Float16* __restrict__ o2)
{
    const int i = blockIdx.x * 256 + threadIdx.x;
    if (i < N3H * KD) {
        o0[i] = (_Float16)w0[i];
        o1[i] = (_Float16)w1[i];
        o2[i] = (_Float16)w2[i];
    }
}

__global__ __launch_bounds__(256) void init_kernel(
    float* __restrict__ amp, float* __restrict__ phase,
    int* __restrict__ nup, int* __restrict__ ndn)
{
    const int i = blockIdx.x * 256 + threadIdx.x;
    if (i < BATCH) { amp[i] = 1.f; phase[i] = 0.f; nup[i] = 0; ndn[i] = 0; }
}

// per-row head + accumulation for `step` (never step 63 when fused)
__device__ __forceinline__ void head_row(
    const _Float16* __restrict__ h1, int m,
    const float* __restrict__ Wamp, const float* __restrict__ bamp,
    const float* __restrict__ Wph,  const float* __restrict__ bph,
    const int* __restrict__ bits,
    float* __restrict__ amp, float* __restrict__ phase,
    int* __restrict__ nup, int* __restrict__ ndn,
    float* __restrict__ out, int step, int lane)
{
    const half8 hv = *(const half8*)(h1 + (size_t)m * HID + lane * 8);
    float d0 = 0.f, d1 = 0.f, d2 = 0.f, d3 = 0.f;
#pragma unroll
    for (int e = 0; e < 8; ++e) {
        const int j = lane * 8 + e;
        const float hn = (float)hv[e];
        d0 += hn * Wamp[j];       d1 += hn * Wamp[HID + j];
        d2 += hn * Wph[j];        d3 += hn * Wph[HID + j];
    }
#pragma unroll
    for (int off = 1; off < 64; off <<= 1) {
        d0 += __shfl_xor(d0, off); d1 += __shfl_xor(d1, off);
        d2 += __shfl_xor(d2, off); d3 += __shfl_xor(d3, off);
    }
    if (lane == 0) {
        const float a0 = d0 + bamp[0];
        const float a1 = d1 + bamp[1];
        const float mx = fmaxf(a0, a1);
        const float e0 = __expf(a0 - mx), e1 = __expf(a1 - mx);
        const float inv = 1.f / (e0 + e1);
        float ya0 = sqrtf(e0 * inv), ya1 = sqrtf(e1 * inv);
        const float p0 = d2 + bph[0];
        const float p1 = d3 + bph[1];
        const float yp0 = PI_F * p0 / (1.f + fabsf(p0));
        const float yp1 = PI_F * p1 / (1.f + fabsf(p1));
        const int even = ((step & 1) == 0);
        const int cnt = even ? nup[m] : ndn[m];
        if (step >= 32) {  // MIN_I
            const int lower = (step >> 1) - 16;
            const float m0v = (cnt > lower) ? ya0 : 0.f;
            const float m1v = (cnt < 16) ? ya1 : 0.f;
            const float nrm = sqrtf(m0v * m0v + m1v * m1v + 1e-12f);
            ya0 = m0v / nrm; ya1 = m1v / nrm;
        }
        const int bi = bits[m * SORB + step];
        const float na = amp[m] * (bi ? ya1 : ya0);
        const float np = phase[m] + (bi ? yp1 : yp0);
        amp[m] = na; phase[m] = np;
        if (bi) { if (even) nup[m] = cnt + 1; else ndn[m] = cnt + 1; }
        if (step == SORB - 1) {
            out[m * 2 + 0] = na;
            out[m * 2 + 1] = np;
        }
    }
}

// ================= step1: z0: gh0+gates0 ; z1: gh1->gB + head(step-1) =================
// BM=64, J=64 (B 192 rows), BK=64. 256 thr = 4 waves (2m x 2j).
// A: direct global->reg fragments (L2-resident h). B: LDS double-buffered,
// staged via global_load_lds; stage(kt+1) issued before compute(kt).
__global__ __launch_bounds__(256) void step1_kernel(
    const _Float16* __restrict__ h0h_c, const _Float16* __restrict__ h1h_c,
    const _Float16* __restrict__ wh0,   const _Float16* __restrict__ wh1,
    const float* __restrict__ Wih0, const int* __restrict__ bits,
    float* __restrict__ h0f, _Float16* __restrict__ h0h_n,
    _Float16* __restrict__ gB, int step,
    const float* __restrict__ Wamp, const float* __restrict__ bamp,
    const float* __restrict__ Wph,  const float* __restrict__ bph,
    float* __restrict__ amp, float* __restrict__ phase,
    int* __restrict__ nup, int* __restrict__ ndn, float* __restrict__ out)
{
    const int z = blockIdx.z;
    const _Float16* Aop = z ? h1h_c : h0h_c;
    const _Float16* Wop = z ? wh1 : wh0;
    const int j0 = blockIdx.x * 64;
    const int m0 = blockIdx.y * 64;

    __shared__ __align__(16) _Float16 Bs[2][192 * BK];   // 2 x 24 KB

    const int tid  = threadIdx.x;
    const int lane = tid & 63;
    const int wid  = tid >> 6;
    const int wm   = wid >> 1, wj = wid & 1;
    const int ku   = lane >> 4;

    floatx4 acc[2][2][3];
    const floatx4 z4 = {0.f, 0.f, 0.f, 0.f};
#pragma unroll
    for (int a = 0; a < 2; ++a)
#pragma unroll
        for (int b = 0; b < 2; ++b)
#pragma unroll
            for (int g = 0; g < 3; ++g) acc[a][b][g] = z4;

    // B staging sources (6 x 16B units per thread), XOR swizzle on global source
    const _Float16* b_srcp[6];
#pragma unroll
    for (int k2 = 0; k2 < 6; ++k2) {
        const int p = tid + k2 * 256, row = p >> 3, c = (p & 7) ^ (row & 7);
        const int grow = (row >> 6) * HID + j0 + (row & 63);
        b_srcp[k2] = Wop + (size_t)grow * KD + c * 8;
    }
    _Float16* b_dst0[6];
    _Float16* b_dst1[6];
#pragma unroll
    for (int k2 = 0; k2 < 6; ++k2) {
        b_dst0[k2] = Bs[0] + (size_t)(k2 * 256 + wid * 64) * 8;
        b_dst1[k2] = Bs[1] + (size_t)(k2 * 256 + wid * 64) * 8;
    }

    // A fragment row bases (direct global)
    const _Float16* a_row[2];
#pragma unroll
    for (int mf = 0; mf < 2; ++mf)
        a_row[mf] = Aop + (size_t)(m0 + wm * 32 + mf * 16 + (lane & 15)) * KD + ku * 8;

    // B fragment offsets (within one buffer)
    int boff[2][3][2];
#pragma unroll
    for (int jf = 0; jf < 2; ++jf)
#pragma unroll
        for (int g = 0; g < 3; ++g) {
            const int r = g * 64 + wj * 32 + jf * 16 + (lane & 15);
#pragma unroll
            for (int kk = 0; kk < 2; ++kk)
                boff[jf][g][kk] = r * BK + (((kk * 4 + ku) ^ (r & 7)) * 8);
        }

    // prologue: stage kt=0 into buf0
#pragma unroll
    for (int k2 = 0; k2 < 6; ++k2) gload16(b_srcp[k2], b_dst0[k2]);
    __syncthreads();

#pragma unroll
    for (int kt = 0; kt < 8; ++kt) {
        // A fragments for current kt (VMEM->VGPR, issued first)
        half8 af[2][2];
#pragma unroll
        for (int mf = 0; mf < 2; ++mf)
#pragma unroll
            for (int kk = 0; kk < 2; ++kk)
                af[mf][kk] = *(const half8*)(a_row[mf] + kt * BK + kk * 32);
        // stage next tile into alternate buffer (flies under this kt's compute)
        if (kt < 7) {
#pragma unroll
            for (int k2 = 0; k2 < 6; ++k2)
                gload16(b_srcp[k2] + (kt + 1) * BK, ((kt & 1) ? b_dst0 : b_dst1)[k2]);
        }
        const _Float16* Bcur = Bs[kt & 1];
#pragma unroll
        for (int kk = 0; kk < 2; ++kk) {
            half8 bf[2][3];
#pragma unroll
            for (int jf = 0; jf < 2; ++jf)
#pragma unroll
                for (int g = 0; g < 3; ++g) bf[jf][g] = *(const half8*)(Bcur + boff[jf][g][kk]);
#pragma unroll
            for (int mf = 0; mf < 2; ++mf)
#pragma unroll
                for (int jf = 0; jf < 2; ++jf)
#pragma unroll
                    for (int g = 0; g < 3; ++g)
                        acc[mf][jf][g] = __builtin_amdgcn_mfma_f32_16x16x32_f16(
                            af[mf][kk], bf[jf][g], acc[mf][jf][g], 0, 0, 0);
        }
        __syncthreads();
    }

    if (z == 0) {
        // fused gates0
#pragma unroll
        for (int mf = 0; mf < 2; ++mf)
#pragma unroll
            for (int jf = 0; jf < 2; ++jf) {
                const floatx4 gr = acc[mf][jf][0];
                const floatx4 gz = acc[mf][jf][1];
                const floatx4 gn = acc[mf][jf][2];
#pragma unroll
                for (int reg = 0; reg < 4; ++reg) {
                    const int m = m0 + wm * 32 + mf * 16 + (lane >> 4) * 4 + reg;
                    const int j = j0 + wj * 32 + jf * 16 + (lane & 15);
                    float gir = 0.f, giz = 0.f, gin = 0.f;
                    if (step > 0) {
                        const int tb = bits[m * SORB + step - 1];
                        gir = Wih0[j * 2 + tb];
                        giz = Wih0[(HID + j) * 2 + tb];
                        gin = Wih0[(2 * HID + j) * 2 + tb];
                    }
                    const float r  = sigmoidf_(gir + gr[reg]);
                    const float zz = sigmoidf_(giz + gz[reg]);
                    const float n  = tanhf_(gin + r * gn[reg]);
                    const size_t idx = (size_t)m * HID + j;
                    const float h  = h0f[idx];
                    const float hn = (1.f - zz) * n + zz * h;
                    h0f[idx]   = hn;
                    h0h_n[idx] = (_Float16)hn;
                }
            }
    } else {
#pragma unroll
        for (int mf = 0; mf < 2; ++mf)
#pragma unroll
            for (int jf = 0; jf < 2; ++jf)
#pragma unroll
                for (int g = 0; g < 3; ++g)
#pragma unroll
                    for (int reg = 0; reg < 4; ++reg) {
                        const int m = m0 + wm * 32 + mf * 16 + (lane >> 4) * 4 + reg;
                        const int j = j0 + wj * 32 + jf * 16 + (lane & 15);
                        gB[(size_t)m * N3H + g * HID + j] = (_Float16)acc[mf][jf][g][reg];
                    }
        // fused head(step-1): 512 z1-blocks x 8 rows (2 rows/wave)
        if (step > 0) {
            const int bid = blockIdx.y * 8 + blockIdx.x;   // 0..511
#pragma unroll
            for (int rr = 0; rr < 2; ++rr) {
                const int m = bid * 8 + wid * 2 + rr;
                head_row(h1h_c, m, Wamp, bamp, Wph, bph, bits,
                         amp, phase, nup, ndn, out, step - 1, lane);
            }
        }
    }
}

// ================= step2: gi1 GEMM + fused gates1 =================
__global__ __launch_bounds__(256) void step2_kernel(
    const _Float16* __restrict__ h0h_n, const _Float16* __restrict__ wi1,
    const _Float16* __restrict__ gB,
    float* __restrict__ h1f, _Float16* __restrict__ h1h_n)
{
    const int j0 = blockIdx.x * 64;
    const int m0 = blockIdx.y * 64;

    __shared__ __align__(16) _Float16 Bs[2][192 * BK];

    const int tid  = threadIdx.x;
    const int lane = tid & 63;
    const int wid  = tid >> 6;
    const int wm   = wid >> 1, wj = wid & 1;
    const int ku   = lane >> 4;

    floatx4 acc[2][2][3];
    const floatx4 z4 = {0.f, 0.f, 0.f, 0.f};
#pragma unroll
    for (int a = 0; a < 2; ++a)
#pragma unroll
        for (int b = 0; b < 2; ++b)
#pragma unroll
            for (int g = 0; g < 3; ++g) acc[a][b][g] = z4;

    const _Float16* b_srcp[6];
#pragma unroll
    for (int k2 = 0; k2 < 6; ++k2) {
        const int p = tid + k2 * 256, row = p >> 3, c = (p & 7) ^ (row & 7);
        const int grow = (row >> 6) * HID + j0 + (row & 63);
        b_srcp[k2] = wi1 + (size_t)grow * KD + c * 8;
    }
    _Float16* b_dst0[6];
    _Float16* b_dst1[6];
#pragma unroll
    for (int k2 = 0; k2 < 6; ++k2) {
        b_dst0[k2] = Bs[0] + (size_t)(k2 * 256 + wid * 64) * 8;
        b_dst1[k2] = Bs[1] + (size_t)(k2 * 256 + wid * 64) * 8;
    }

    const _Float16* a_row[2];
#pragma unroll
    for (int mf = 0; mf < 2; ++mf)
        a_row[mf] = h0h_n + (size_t)(m0 + wm * 32 + mf * 16 + (lane & 15)) * KD + ku * 8;

    int boff[2][3][2];
#pragma unroll
    for (int jf = 0; jf < 2; ++jf)
#pragma unroll
        for (int g = 0; g < 3; ++g) {
            const int r = g * 64 + wj * 32 + jf * 16 + (lane & 15);
#pragma unroll
            for (int kk = 0; kk < 2; ++kk)
                boff[jf][g][kk] = r * BK + (((kk * 4 + ku) ^ (r & 7)) * 8);
        }

#pragma unroll
    for (int k2 = 0; k2 < 6; ++k2) gload16(b_srcp[k2], b_dst0[k2]);
    __syncthreads();

#pragma unroll
    for (int kt = 0; kt < 8; ++kt) {
        half8 af[2][2];
#pragma unroll
        for (int mf = 0; mf < 2; ++mf)
#pragma unroll
            for (int kk = 0; kk < 2; ++kk)
                af[mf][kk] = *(const half8*)(a_row[mf] + kt * BK + kk * 32);
        if (kt < 7) {
#pragma unroll
            for (int k2 = 0; k2 < 6; ++k2)
                gload16(b_srcp[k2] + (kt + 1) * BK, ((kt & 1) ? b_dst0 : b_dst1)[k2]);
        }
        const _Float16* Bcur = Bs[kt & 1];
#pragma unroll
        for (int kk = 0; kk < 2; ++kk) {
            half8 bf[2][3];
#pragma unroll
            for (int jf = 0; jf < 2; ++jf)
#pragma unroll
                for (int g = 0; g < 3; ++g) bf[jf][g] = *(const half8*)(Bcur + boff[jf][g][kk]);
#pragma unroll
            for (int mf = 0; mf < 2; ++mf)
#pragma unroll
                for (int jf = 0; jf < 2; ++jf)
#pragma unroll
                    for (int g = 0; g < 3; ++g)
                        acc[mf][jf][g] = __builtin_amdgcn_mfma_f32_16x16x32_f16(
                            af[mf][kk], bf[jf][g], acc[mf][jf][g], 0, 0, 0);
        }
        __syncthreads();
    }

    // fused gates1
#pragma unroll
    for (int mf = 0; mf < 2; ++mf)
#pragma unroll
        for (int jf = 0; jf < 2; ++jf) {
            const floatx4 gr = acc[mf][jf][0];
            const floatx4 gz = acc[mf][jf][1];
            const floatx4 gn = acc[mf][jf][2];
#pragma unroll
            for (int reg = 0; reg < 4; ++reg) {
                const int m = m0 + wm * 32 + mf * 16 + (lane >> 4) * 4 + reg;
                const int j = j0 + wj * 32 + jf * 16 + (lane & 15);
                const size_t gbase = (size_t)m * N3H;
                const float ghr = (float)gB[gbase + j];
                const float ghz = (float)gB[gbase + HID + j];
                const float ghn = (float)gB[gbase + 2 * HID + j];
                const float r  = sigmoidf_(gr[reg] + ghr);
                const float zz = sigmoidf_(gz[reg] + ghz);
                const float n  = tanhf_(gn[reg] + r * ghn);
                const size_t idx = (size_t)m * HID + j;
                const float h  = h1f[idx];
                const float hn = (1.f - zz) * n + zz * h;
                h1f[idx]   = hn;
                h1h_n[idx] = (_Float16)hn;
            }
        }
}

// ================= final head (step 63) =================
__global__ __launch_bounds__(256) void head_kernel(
    const _Float16* __restrict__ h1h_n,
    const float* __restrict__ Wamp, const float* __restrict__ bamp,
    const float* __restrict__ Wph,  const float* __restrict__ bph,
    const int* __restrict__ bits,
    float* __restrict__ amp, float* __restrict__ phase,
    int* __restrict__ nup, int* __restrict__ ndn,
    float* __restrict__ out, int step)
{
    const int lane = threadIdx.x & 63;
    const int m    = blockIdx.x * 4 + (threadIdx.x >> 6);
    head_row(h1h_n, m, Wamp, bamp, Wph, bph, bits, amp, phase, nup, ndn, out, step, lane);
}

extern "C" void kernel_launch(void* const* d_in, const int* in_sizes, int n_in,
                              void* d_out, int out_size, void* d_ws, size_t ws_size,
                              hipStream_t stream) {
    const int*   bits = (const int*)d_in[0];
    const float* Wih0 = (const float*)d_in[1];
    const float* Whh0 = (const float*)d_in[2];
    const float* Wih1 = (const float*)d_in[3];
    const float* Whh1 = (const float*)d_in[4];
    const float* Wamp = (const float*)d_in[5];
    const float* bamp = (const float*)d_in[6];
    const float* Wph  = (const float*)d_in[7];
    const float* bph  = (const float*)d_in[8];
    float* out = (float*)d_out;

    char* ws = (char*)d_ws;
    size_t off = 0;
    auto alloc = [&](size_t bytes) {
        void* p = ws + off;
        off = (off + bytes + 255) & ~(size_t)255;
        return p;
    };
    _Float16* wh0 = (_Float16*)alloc((size_t)N3H * KD * 2);
    _Float16* wi1 = (_Float16*)alloc((size_t)N3H * KD * 2);
    _Float16* wh1 = (_Float16*)alloc((size_t)N3H * KD * 2);
    float*    h0f = (float*)alloc((size_t)BATCH * HID * 4);
    float*    h1f = (float*)alloc((size_t)BATCH * HID * 4);
    _Float16* h0hA = (_Float16*)alloc((size_t)BATCH * HID * 2);
    _Float16* h0hB = (_Float16*)alloc((size_t)BATCH * HID * 2);
    _Float16* h1hA = (_Float16*)alloc((size_t)BATCH * HID * 2);
    _Float16* h1hB = (_Float16*)alloc((size_t)BATCH * HID * 2);
    _Float16* gB  = (_Float16*)alloc((size_t)BATCH * N3H * 2);
    float*    amp   = (float*)alloc((size_t)BATCH * 4);
    float*    phase = (float*)alloc((size_t)BATCH * 4);
    int*      nup   = (int*)alloc((size_t)BATCH * 4);
    int*      ndn   = (int*)alloc((size_t)BATCH * 4);

    _Float16* h0h[2] = {h0hA, h0hB};
    _Float16* h1h[2] = {h1hA, h1hB};

    hipMemsetAsync(h0f, 0, (size_t)BATCH * HID * 4, stream);
    hipMemsetAsync(h1f, 0, (size_t)BATCH * HID * 4, stream);
    hipMemsetAsync(h0hA, 0, (size_t)BATCH * HID * 2, stream);
    hipMemsetAsync(h1hA, 0, (size_t)BATCH * HID * 2, stream);
    convw_kernel<<<(N3H * KD + 255) / 256, 256, 0, stream>>>(Whh0, Wih1, Whh1, wh0, wi1, wh1);
    init_kernel<<<BATCH / 256, 256, 0, stream>>>(amp, phase, nup, ndn);

    for (int s = 0; s < SORB; ++s) {
        const int cur = s & 1, nxt = cur ^ 1;
        step1_kernel<<<dim3(8, 64, 2), 256, 0, stream>>>(
            h0h[cur], h1h[cur], wh0, wh1, Wih0, bits, h0f, h0h[nxt], gB, s,
            Wamp, bamp, Wph, bph, amp, phase, nup, ndn, out);
        step2_kernel<<<dim3(8, 64, 1), 256, 0, stream>>>(
            h0h[nxt], wi1, gB, h1f, h1h[nxt]);
    }
    head_kernel<<<BATCH / 4, 256, 0, stream>>>(
        h1h[0], Wamp, bamp, Wph, bph, bits, amp, phase, nup, ndn, out, SORB - 1);
}

// Round 14
// 3623.114 us; speedup vs baseline: 3.4200x; 1.1237x over previous
//
#include <hip/hip_runtime.h>
#include <hip/hip_bf16.h>

#define SORB  64
#define HID   512
#define BATCH 4096
#define N3H   1536
#define KD    512
#define BK    64
#define PI_F  3.14159265358979f

typedef _Float16 half8 __attribute__((ext_vector_type(8)));
typedef float    floatx4 __attribute__((ext_vector_type(4)));

__device__ __forceinline__ void gload16(const void* g, void* l) {
    __builtin_amdgcn_global_load_lds(
        (const __attribute__((address_space(1))) void*)g,
        (__attribute__((address_space(3))) void*)l, 16, 0, 0);
}

__device__ __forceinline__ float sigmoidf_(float x) { return 1.f / (1.f + __expf(-x)); }
__device__ __forceinline__ float tanhf_(float x) {
    x = fminf(fmaxf(x, -15.f), 15.f);
    const float e2 = __expf(2.f * x);
    return (e2 - 1.f) / (e2 + 1.f);
}

__global__ __launch_bounds__(256) void convw_kernel(
    const float* __restrict__ w0, const float* __restrict__ w1, const float* __restrict__ w2,
    _Float16* __restrict__ o0, _Float16* __restrict__ o1, _Float16* __restrict__ o2)
{
    const int i = blockIdx.x * 256 + threadIdx.x;
    if (i < N3H * KD) {
        o0[i] = (_Float16)w0[i];
        o1[i] = (_Float16)w1[i];
        o2[i] = (_Float16)w2[i];
    }
}

__global__ __launch_bounds__(256) void init_kernel(
    float* __restrict__ amp, float* __restrict__ phase,
    int* __restrict__ nup, int* __restrict__ ndn)
{
    const int i = blockIdx.x * 256 + threadIdx.x;
    if (i < BATCH) { amp[i] = 1.f; phase[i] = 0.f; nup[i] = 0; ndn[i] = 0; }
}

// per-row head + accumulation for `step`
__device__ __forceinline__ void head_row(
    const _Float16* __restrict__ h1, int m,
    const float* __restrict__ Wamp, const float* __restrict__ bamp,
    const float* __restrict__ Wph,  const float* __restrict__ bph,
    const int* __restrict__ bits,
    float* __restrict__ amp, float* __restrict__ phase,
    int* __restrict__ nup, int* __restrict__ ndn,
    float* __restrict__ out, int step, int lane)
{
    const half8 hv = *(const half8*)(h1 + (size_t)m * HID + lane * 8);
    float d0 = 0.f, d1 = 0.f, d2 = 0.f, d3 = 0.f;
#pragma unroll
    for (int e = 0; e < 8; ++e) {
        const int j = lane * 8 + e;
        const float hn = (float)hv[e];
        d0 += hn * Wamp[j];       d1 += hn * Wamp[HID + j];
        d2 += hn * Wph[j];        d3 += hn * Wph[HID + j];
    }
#pragma unroll
    for (int off = 1; off < 64; off <<= 1) {
        d0 += __shfl_xor(d0, off); d1 += __shfl_xor(d1, off);
        d2 += __shfl_xor(d2, off); d3 += __shfl_xor(d3, off);
    }
    if (lane == 0) {
        const float a0 = d0 + bamp[0];
        const float a1 = d1 + bamp[1];
        const float mx = fmaxf(a0, a1);
        const float e0 = __expf(a0 - mx), e1 = __expf(a1 - mx);
        const float inv = 1.f / (e0 + e1);
        float ya0 = sqrtf(e0 * inv), ya1 = sqrtf(e1 * inv);
        const float p0 = d2 + bph[0];
        const float p1 = d3 + bph[1];
        const float yp0 = PI_F * p0 / (1.f + fabsf(p0));
        const float yp1 = PI_F * p1 / (1.f + fabsf(p1));
        const int even = ((step & 1) == 0);
        const int cnt = even ? nup[m] : ndn[m];
        if (step >= 32) {  // MIN_I
            const int lower = (step >> 1) - 16;
            const float m0v = (cnt > lower) ? ya0 : 0.f;
            const float m1v = (cnt < 16) ? ya1 : 0.f;
            const float nrm = sqrtf(m0v * m0v + m1v * m1v + 1e-12f);
            ya0 = m0v / nrm; ya1 = m1v / nrm;
        }
        const int bi = bits[m * SORB + step];
        const float na = amp[m] * (bi ? ya1 : ya0);
        const float np = phase[m] + (bi ? yp1 : yp0);
        amp[m] = na; phase[m] = np;
        if (bi) { if (even) nup[m] = cnt + 1; else ndn[m] = cnt + 1; }
        if (step == SORB - 1) {
            out[m * 2 + 0] = na;
            out[m * 2 + 1] = np;
        }
    }
}

// ================= step1: z0: gh0+gates0 ; z1: gh1->gB + fused head(step-1) ===========
// 1024 flat blocks, XCD-partitioned: blockIdx%8 < 4 -> z=0 (wh0), >=4 -> z=1 (wh1)
// so each XCD's L2 holds only ONE 1.57MB weight matrix.
// Per tile: BM=64, J=64 (B-tile 192 rows), BK=64, R11's single-buffer K-loop.
__global__ __launch_bounds__(256) void step1_kernel(
    const _Float16* __restrict__ h0h_c, const _Float16* __restrict__ h1h_c,
    const _Float16* __restrict__ wh0,   const _Float16* __restrict__ wh1,
    const float* __restrict__ Wih0, const int* __restrict__ bits,
    float* __restrict__ h0f, _Float16* __restrict__ h0h_n,
    _Float16* __restrict__ gB, int step,
    const float* __restrict__ Wamp, const float* __restrict__ bamp,
    const float* __restrict__ Wph,  const float* __restrict__ bph,
    float* __restrict__ amp, float* __restrict__ phase,
    int* __restrict__ nup, int* __restrict__ ndn, float* __restrict__ out)
{
    const int id  = blockIdx.x;
    const int r8  = id & 7;
    const int z   = (r8 >= 4) ? 1 : 0;
    const int t   = (id >> 3) * 4 + (r8 & 3);     // tile index within z, [0,512)
    const int j0  = (t & 7) * 64;
    const int m0  = (t >> 3) * 64;

    const _Float16* Aop = z ? h1h_c : h0h_c;
    const _Float16* Wop = z ? wh1 : wh0;

    __shared__ __align__(16) _Float16 As[64 * BK];    // 8 KB
    __shared__ __align__(16) _Float16 Bs[192 * BK];   // 24 KB

    const int tid  = threadIdx.x;
    const int lane = tid & 63;
    const int wid  = tid >> 6;
    const int wm   = wid >> 1, wj = wid & 1;
    const int ku   = lane >> 4;

    floatx4 acc[2][2][3];
    const floatx4 z4 = {0.f, 0.f, 0.f, 0.f};
#pragma unroll
    for (int a = 0; a < 2; ++a)
#pragma unroll
        for (int b = 0; b < 2; ++b)
#pragma unroll
            for (int g = 0; g < 3; ++g) acc[a][b][g] = z4;

    const _Float16* a_srcp[2];
#pragma unroll
    for (int k2 = 0; k2 < 2; ++k2) {
        const int p = tid + k2 * 256, row = p >> 3, c = (p & 7) ^ (row & 7);
        a_srcp[k2] = Aop + (size_t)(m0 + row) * KD + c * 8;
    }
    const _Float16* b_srcp[6];
#pragma unroll
    for (int k2 = 0; k2 < 6; ++k2) {
        const int p = tid + k2 * 256, row = p >> 3, c = (p & 7) ^ (row & 7);
        const int grow = (row >> 6) * HID + j0 + (row & 63);
        b_srcp[k2] = Wop + (size_t)grow * KD + c * 8;
    }
    _Float16* a_dst[2];
#pragma unroll
    for (int k2 = 0; k2 < 2; ++k2) a_dst[k2] = As + (size_t)(k2 * 256 + wid * 64) * 8;
    _Float16* b_dst[6];
#pragma unroll
    for (int k2 = 0; k2 < 6; ++k2) b_dst[k2] = Bs + (size_t)(k2 * 256 + wid * 64) * 8;

    int aoff[2][2], boff[2][3][2];
#pragma unroll
    for (int mf = 0; mf < 2; ++mf) {
        const int r = wm * 32 + mf * 16 + (lane & 15);
#pragma unroll
        for (int kk = 0; kk < 2; ++kk)
            aoff[mf][kk] = r * BK + (((kk * 4 + ku) ^ (r & 7)) * 8);
    }
#pragma unroll
    for (int jf = 0; jf < 2; ++jf)
#pragma unroll
        for (int g = 0; g < 3; ++g) {
            const int r = g * 64 + wj * 32 + jf * 16 + (lane & 15);
#pragma unroll
            for (int kk = 0; kk < 2; ++kk)
                boff[jf][g][kk] = r * BK + (((kk * 4 + ku) ^ (r & 7)) * 8);
        }

    for (int kt = 0; kt < 8; ++kt) {
        const int k0 = kt * BK;
#pragma unroll
        for (int k2 = 0; k2 < 2; ++k2) gload16(a_srcp[k2] + k0, a_dst[k2]);
#pragma unroll
        for (int k2 = 0; k2 < 6; ++k2) gload16(b_srcp[k2] + k0, b_dst[k2]);
        __syncthreads();
#pragma unroll
        for (int kk = 0; kk < 2; ++kk) {
            half8 af[2], bf[2][3];
#pragma unroll
            for (int mf = 0; mf < 2; ++mf) af[mf] = *(const half8*)(As + aoff[mf][kk]);
#pragma unroll
            for (int jf = 0; jf < 2; ++jf)
#pragma unroll
                for (int g = 0; g < 3; ++g) bf[jf][g] = *(const half8*)(Bs + boff[jf][g][kk]);
#pragma unroll
            for (int mf = 0; mf < 2; ++mf)
#pragma unroll
                for (int jf = 0; jf < 2; ++jf)
#pragma unroll
                    for (int g = 0; g < 3; ++g)
                        acc[mf][jf][g] = __builtin_amdgcn_mfma_f32_16x16x32_f16(
                            af[mf], bf[jf][g], acc[mf][jf][g], 0, 0, 0);
        }
        __syncthreads();
    }

    if (z == 0) {
        // fused gates0
#pragma unroll
        for (int mf = 0; mf < 2; ++mf)
#pragma unroll
            for (int jf = 0; jf < 2; ++jf) {
                const floatx4 gr = acc[mf][jf][0];
                const floatx4 gz = acc[mf][jf][1];
                const floatx4 gn = acc[mf][jf][2];
#pragma unroll
                for (int reg = 0; reg < 4; ++reg) {
                    const int m = m0 + wm * 32 + mf * 16 + (lane >> 4) * 4 + reg;
                    const int j = j0 + wj * 32 + jf * 16 + (lane & 15);
                    float gir = 0.f, giz = 0.f, gin = 0.f;
                    if (step > 0) {
                        const int tb = bits[m * SORB + step - 1];
                        gir = Wih0[j * 2 + tb];
                        giz = Wih0[(HID + j) * 2 + tb];
                        gin = Wih0[(2 * HID + j) * 2 + tb];
                    }
                    const float r  = sigmoidf_(gir + gr[reg]);
                    const float zz = sigmoidf_(giz + gz[reg]);
                    const float n  = tanhf_(gin + r * gn[reg]);
                    const size_t idx = (size_t)m * HID + j;
                    const float h  = h0f[idx];
                    const float hn = (1.f - zz) * n + zz * h;
                    h0f[idx]   = hn;
                    h0h_n[idx] = (_Float16)hn;
                }
            }
    } else {
#pragma unroll
        for (int mf = 0; mf < 2; ++mf)
#pragma unroll
            for (int jf = 0; jf < 2; ++jf)
#pragma unroll
                for (int g = 0; g < 3; ++g)
#pragma unroll
                    for (int reg = 0; reg < 4; ++reg) {
                        const int m = m0 + wm * 32 + mf * 16 + (lane >> 4) * 4 + reg;
                        const int j = j0 + wj * 32 + jf * 16 + (lane & 15);
                        gB[(size_t)m * N3H + g * HID + j] = (_Float16)acc[mf][jf][g][reg];
                    }
        // fused head(step-1): 512 z1-blocks x 8 rows (2 rows/wave)
        if (step > 0) {
#pragma unroll
            for (int rr = 0; rr < 2; ++rr) {
                const int m = t * 8 + wid * 2 + rr;
                head_row(h1h_c, m, Wamp, bamp, Wph, bph, bits,
                         amp, phase, nup, ndn, out, step - 1, lane);
            }
        }
    }
}

// ================= step2: gi1 GEMM + fused gates1 (R11 form) =================
__global__ __launch_bounds__(256) void step2_kernel(
    const _Float16* __restrict__ h0h_n, const _Float16* __restrict__ wi1,
    const _Float16* __restrict__ gB,
    float* __restrict__ h1f, _Float16* __restrict__ h1h_n)
{
    const int j0 = blockIdx.x * 64;
    const int m0 = blockIdx.y * 64;

    __shared__ __align__(16) _Float16 As[64 * BK];
    __shared__ __align__(16) _Float16 Bs[192 * BK];

    const int tid  = threadIdx.x;
    const int lane = tid & 63;
    const int wid  = tid >> 6;
    const int wm   = wid >> 1, wj = wid & 1;
    const int ku   = lane >> 4;

    floatx4 acc[2][2][3];
    const floatx4 z4 = {0.f, 0.f, 0.f, 0.f};
#pragma unroll
    for (int a = 0; a < 2; ++a)
#pragma unroll
        for (int b = 0; b < 2; ++b)
#pragma unroll
            for (int g = 0; g < 3; ++g) acc[a][b][g] = z4;

    const _Float16* a_srcp[2];
#pragma unroll
    for (int k2 = 0; k2 < 2; ++k2) {
        const int p = tid + k2 * 256, row = p >> 3, c = (p & 7) ^ (row & 7);
        a_srcp[k2] = h0h_n + (size_t)(m0 + row) * KD + c * 8;
    }
    const _Float16* b_srcp[6];
#pragma unroll
    for (int k2 = 0; k2 < 6; ++k2) {
        const int p = tid + k2 * 256, row = p >> 3, c = (p & 7) ^ (row & 7);
        const int grow = (row >> 6) * HID + j0 + (row & 63);
        b_srcp[k2] = wi1 + (size_t)grow * KD + c * 8;
    }
    _Float16* a_dst[2];
#pragma unroll
    for (int k2 = 0; k2 < 2; ++k2) a_dst[k2] = As + (size_t)(k2 * 256 + wid * 64) * 8;
    _Float16* b_dst[6];
#pragma unroll
    for (int k2 = 0; k2 < 6; ++k2) b_dst[k2] = Bs + (size_t)(k2 * 256 + wid * 64) * 8;

    int aoff[2][2], boff[2][3][2];
#pragma unroll
    for (int mf = 0; mf < 2; ++mf) {
        const int r = wm * 32 + mf * 16 + (lane & 15);
#pragma unroll
        for (int kk = 0; kk < 2; ++kk)
            aoff[mf][kk] = r * BK + (((kk * 4 + ku) ^ (r & 7)) * 8);
    }
#pragma unroll
    for (int jf = 0; jf < 2; ++jf)
#pragma unroll
        for (int g = 0; g < 3; ++g) {
            const int r = g * 64 + wj * 32 + jf * 16 + (lane & 15);
#pragma unroll
            for (int kk = 0; kk < 2; ++kk)
                boff[jf][g][kk] = r * BK + (((kk * 4 + ku) ^ (r & 7)) * 8);
        }

    for (int kt = 0; kt < 8; ++kt) {
        const int k0 = kt * BK;
#pragma unroll
        for (int k2 = 0; k2 < 2; ++k2) gload16(a_srcp[k2] + k0, a_dst[k2]);
#pragma unroll
        for (int k2 = 0; k2 < 6; ++k2) gload16(b_srcp[k2] + k0, b_dst[k2]);
        __syncthreads();
#pragma unroll
        for (int kk = 0; kk < 2; ++kk) {
            half8 af[2], bf[2][3];
#pragma unroll
            for (int mf = 0; mf < 2; ++mf) af[mf] = *(const half8*)(As + aoff[mf][kk]);
#pragma unroll
            for (int jf = 0; jf < 2; ++jf)
#pragma unroll
                for (int g = 0; g < 3; ++g) bf[jf][g] = *(const half8*)(Bs + boff[jf][g][kk]);
#pragma unroll
            for (int mf = 0; mf < 2; ++mf)
#pragma unroll
                for (int jf = 0; jf < 2; ++jf)
#pragma unroll
                    for (int g = 0; g < 3; ++g)
                        acc[mf][jf][g] = __builtin_amdgcn_mfma_f32_16x16x32_f16(
                            af[mf], bf[jf][g], acc[mf][jf][g], 0, 0, 0);
        }
        __syncthreads();
    }

    // fused gates1
#pragma unroll
    for (int mf = 0; mf < 2; ++mf)
#pragma unroll
        for (int jf = 0; jf < 2; ++jf) {
            const floatx4 gr = acc[mf][jf][0];
            const floatx4 gz = acc[mf][jf][1];
            const floatx4 gn = acc[mf][jf][2];
#pragma unroll
            for (int reg = 0; reg < 4; ++reg) {
                const int m = m0 + wm * 32 + mf * 16 + (lane >> 4) * 4 + reg;
                const int j = j0 + wj * 32 + jf * 16 + (lane & 15);
                const size_t gbase = (size_t)m * N3H;
                const float ghr = (float)gB[gbase + j];
                const float ghz = (float)gB[gbase + HID + j];
                const float ghn = (float)gB[gbase + 2 * HID + j];
                const float r  = sigmoidf_(gr[reg] + ghr);
                const float zz = sigmoidf_(gz[reg] + ghz);
                const float n  = tanhf_(gn[reg] + r * ghn);
                const size_t idx = (size_t)m * HID + j;
                const float h  = h1f[idx];
                const float hn = (1.f - zz) * n + zz * h;
                h1f[idx]   = hn;
                h1h_n[idx] = (_Float16)hn;
            }
        }
}

// ================= final head (step 63) =================
__global__ __launch_bounds__(256) void head_kernel(
    const _Float16* __restrict__ h1h_n,
    const float* __restrict__ Wamp, const float* __restrict__ bamp,
    const float* __restrict__ Wph,  const float* __restrict__ bph,
    const int* __restrict__ bits,
    float* __restrict__ amp, float* __restrict__ phase,
    int* __restrict__ nup, int* __restrict__ ndn,
    float* __restrict__ out, int step)
{
    const int lane = threadIdx.x & 63;
    const int m    = blockIdx.x * 4 + (threadIdx.x >> 6);
    head_row(h1h_n, m, Wamp, bamp, Wph, bph, bits, amp, phase, nup, ndn, out, step, lane);
}

extern "C" void kernel_launch(void* const* d_in, const int* in_sizes, int n_in,
                              void* d_out, int out_size, void* d_ws, size_t ws_size,
                              hipStream_t stream) {
    const int*   bits = (const int*)d_in[0];
    const float* Wih0 = (const float*)d_in[1];
    const float* Whh0 = (const float*)d_in[2];
    const float* Wih1 = (const float*)d_in[3];
    const float* Whh1 = (const float*)d_in[4];
    const float* Wamp = (const float*)d_in[5];
    const float* bamp = (const float*)d_in[6];
    const float* Wph  = (const float*)d_in[7];
    const float* bph  = (const float*)d_in[8];
    float* out = (float*)d_out;

    char* ws = (char*)d_ws;
    size_t off = 0;
    auto alloc = [&](size_t bytes) {
        void* p = ws + off;
        off = (off + bytes + 255) & ~(size_t)255;
        return p;
    };
    _Float16* wh0 = (_Float16*)alloc((size_t)N3H * KD * 2);
    _Float16* wi1 = (_Float16*)alloc((size_t)N3H * KD * 2);
    _Float16* wh1 = (_Float16*)alloc((size_t)N3H * KD * 2);
    float*    h0f = (float*)alloc((size_t)BATCH * HID * 4);
    float*    h1f = (float*)alloc((size_t)BATCH * HID * 4);
    _Float16* h0hA = (_Float16*)alloc((size_t)BATCH * HID * 2);
    _Float16* h0hB = (_Float16*)alloc((size_t)BATCH * HID * 2);
    _Float16* h1hA = (_Float16*)alloc((size_t)BATCH * HID * 2);
    _Float16* h1hB = (_Float16*)alloc((size_t)BATCH * HID * 2);
    _Float16* gB  = (_Float16*)alloc((size_t)BATCH * N3H * 2);
    float*    amp   = (float*)alloc((size_t)BATCH * 4);
    float*    phase = (float*)alloc((size_t)BATCH * 4);
    int*      nup   = (int*)alloc((size_t)BATCH * 4);
    int*      ndn   = (int*)alloc((size_t)BATCH * 4);

    _Float16* h0h[2] = {h0hA, h0hB};
    _Float16* h1h[2] = {h1hA, h1hB};

    hipMemsetAsync(h0f, 0, (size_t)BATCH * HID * 4, stream);
    hipMemsetAsync(h1f, 0, (size_t)BATCH * HID * 4, stream);
    hipMemsetAsync(h0hA, 0, (size_t)BATCH * HID * 2, stream);
    hipMemsetAsync(h1hA, 0, (size_t)BATCH * HID * 2, stream);
    convw_kernel<<<(N3H * KD + 255) / 256, 256, 0, stream>>>(Whh0, Wih1, Whh1, wh0, wi1, wh1);
    init_kernel<<<BATCH / 256, 256, 0, stream>>>(amp, phase, nup, ndn);

    for (int s = 0; s < SORB; ++s) {
        const int cur = s & 1, nxt = cur ^ 1;
        step1_kernel<<<1024, 256, 0, stream>>>(
            h0h[cur], h1h[cur], wh0, wh1, Wih0, bits, h0f, h0h[nxt], gB, s,
            Wamp, bamp, Wph, bph, amp, phase, nup, ndn, out);
        step2_kernel<<<dim3(8, 64), 256, 0, stream>>>(
            h0h[nxt], wi1, gB, h1f, h1h[nxt]);
    }
    head_kernel<<<BATCH / 4, 256, 0, stream>>>(
        h1h[0], Wamp, bamp, Wph, bph, bits, amp, phase, nup, ndn, out, SORB - 1);
}

// Round 15
// 3400.141 us; speedup vs baseline: 3.6442x; 1.0656x over previous
//
#include <hip/hip_runtime.h>
#include <hip/hip_bf16.h>

#define SORB  64
#define HID   512
#define BATCH 4096
#define N3H   1536
#define KD    512
#define BK    64
#define PI_F  3.14159265358979f

typedef _Float16 half8 __attribute__((ext_vector_type(8)));
typedef float    floatx4 __attribute__((ext_vector_type(4)));

__device__ __forceinline__ void gload16(const void* g, void* l) {
    __builtin_amdgcn_global_load_lds(
        (const __attribute__((address_space(1))) void*)g,
        (__attribute__((address_space(3))) void*)l, 16, 0, 0);
}

__device__ __forceinline__ float sigmoidf_(float x) { return 1.f / (1.f + __expf(-x)); }
__device__ __forceinline__ float tanhf_(float x) {
    x = fminf(fmaxf(x, -15.f), 15.f);
    const float e2 = __expf(2.f * x);
    return (e2 - 1.f) / (e2 + 1.f);
}

__global__ __launch_bounds__(256) void convw_kernel(
    const float* __restrict__ w0, const float* __restrict__ w1, const float* __restrict__ w2,
    _Float16* __restrict__ o0, _Float16* __restrict__ o1, _Float16* __restrict__ o2)
{
    const int i = blockIdx.x * 256 + threadIdx.x;
    if (i < N3H * KD) {
        o0[i] = (_Float16)w0[i];
        o1[i] = (_Float16)w1[i];
        o2[i] = (_Float16)w2[i];
    }
}

__global__ __launch_bounds__(256) void init_kernel(
    float* __restrict__ amp, float* __restrict__ phase,
    int* __restrict__ nup, int* __restrict__ ndn)
{
    const int i = blockIdx.x * 256 + threadIdx.x;
    if (i < BATCH) { amp[i] = 1.f; phase[i] = 0.f; nup[i] = 0; ndn[i] = 0; }
}

// per-row head + accumulation for `step`
__device__ __forceinline__ void head_row(
    const _Float16* __restrict__ h1, int m,
    const float* __restrict__ Wamp, const float* __restrict__ bamp,
    const float* __restrict__ Wph,  const float* __restrict__ bph,
    const int* __restrict__ bits,
    float* __restrict__ amp, float* __restrict__ phase,
    int* __restrict__ nup, int* __restrict__ ndn,
    float* __restrict__ out, int step, int lane)
{
    const half8 hv = *(const half8*)(h1 + (size_t)m * HID + lane * 8);
    float d0 = 0.f, d1 = 0.f, d2 = 0.f, d3 = 0.f;
#pragma unroll
    for (int e = 0; e < 8; ++e) {
        const int j = lane * 8 + e;
        const float hn = (float)hv[e];
        d0 += hn * Wamp[j];       d1 += hn * Wamp[HID + j];
        d2 += hn * Wph[j];        d3 += hn * Wph[HID + j];
    }
#pragma unroll
    for (int off = 1; off < 64; off <<= 1) {
        d0 += __shfl_xor(d0, off); d1 += __shfl_xor(d1, off);
        d2 += __shfl_xor(d2, off); d3 += __shfl_xor(d3, off);
    }
    if (lane == 0) {
        const float a0 = d0 + bamp[0];
        const float a1 = d1 + bamp[1];
        const float mx = fmaxf(a0, a1);
        const float e0 = __expf(a0 - mx), e1 = __expf(a1 - mx);
        const float inv = 1.f / (e0 + e1);
        float ya0 = sqrtf(e0 * inv), ya1 = sqrtf(e1 * inv);
        const float p0 = d2 + bph[0];
        const float p1 = d3 + bph[1];
        const float yp0 = PI_F * p0 / (1.f + fabsf(p0));
        const float yp1 = PI_F * p1 / (1.f + fabsf(p1));
        const int even = ((step & 1) == 0);
        const int cnt = even ? nup[m] : ndn[m];
        if (step >= 32) {  // MIN_I
            const int lower = (step >> 1) - 16;
            const float m0v = (cnt > lower) ? ya0 : 0.f;
            const float m1v = (cnt < 16) ? ya1 : 0.f;
            const float nrm = sqrtf(m0v * m0v + m1v * m1v + 1e-12f);
            ya0 = m0v / nrm; ya1 = m1v / nrm;
        }
        const int bi = bits[m * SORB + step];
        const float na = amp[m] * (bi ? ya1 : ya0);
        const float np = phase[m] + (bi ? yp1 : yp0);
        amp[m] = na; phase[m] = np;
        if (bi) { if (even) nup[m] = cnt + 1; else ndn[m] = cnt + 1; }
        if (step == SORB - 1) {
            out[m * 2 + 0] = na;
            out[m * 2 + 1] = np;
        }
    }
}

// ================= step1: z0: gh0+gates0 ; z1: gh1->gB + fused head(step-1) ===========
// R11 grid dim3(8,64,2), R11 K-loop (single-buffer, gload_lds, BK=64).
__global__ __launch_bounds__(256) void step1_kernel(
    const _Float16* __restrict__ h0h_c, const _Float16* __restrict__ h1h_c,
    const _Float16* __restrict__ wh0,   const _Float16* __restrict__ wh1,
    const float* __restrict__ Wih0, const int* __restrict__ bits,
    float* __restrict__ h0f, _Float16* __restrict__ h0h_n,
    _Float16* __restrict__ gB, int step,
    const float* __restrict__ Wamp, const float* __restrict__ bamp,
    const float* __restrict__ Wph,  const float* __restrict__ bph,
    float* __restrict__ amp, float* __restrict__ phase,
    int* __restrict__ nup, int* __restrict__ ndn, float* __restrict__ out)
{
    const int z = blockIdx.z;
    const _Float16* Aop = z ? h1h_c : h0h_c;
    const _Float16* Wop = z ? wh1 : wh0;
    const int j0 = blockIdx.x * 64;
    const int m0 = blockIdx.y * 64;

    __shared__ __align__(16) _Float16 As[64 * BK];    // 8 KB
    __shared__ __align__(16) _Float16 Bs[192 * BK];   // 24 KB

    const int tid  = threadIdx.x;
    const int lane = tid & 63;
    const int wid  = tid >> 6;
    const int wm   = wid >> 1, wj = wid & 1;
    const int ku   = lane >> 4;

    floatx4 acc[2][2][3];
    const floatx4 z4 = {0.f, 0.f, 0.f, 0.f};
#pragma unroll
    for (int a = 0; a < 2; ++a)
#pragma unroll
        for (int b = 0; b < 2; ++b)
#pragma unroll
            for (int g = 0; g < 3; ++g) acc[a][b][g] = z4;

    const _Float16* a_srcp[2];
#pragma unroll
    for (int k2 = 0; k2 < 2; ++k2) {
        const int p = tid + k2 * 256, row = p >> 3, c = (p & 7) ^ (row & 7);
        a_srcp[k2] = Aop + (size_t)(m0 + row) * KD + c * 8;
    }
    const _Float16* b_srcp[6];
#pragma unroll
    for (int k2 = 0; k2 < 6; ++k2) {
        const int p = tid + k2 * 256, row = p >> 3, c = (p & 7) ^ (row & 7);
        const int grow = (row >> 6) * HID + j0 + (row & 63);
        b_srcp[k2] = Wop + (size_t)grow * KD + c * 8;
    }
    _Float16* a_dst[2];
#pragma unroll
    for (int k2 = 0; k2 < 2; ++k2) a_dst[k2] = As + (size_t)(k2 * 256 + wid * 64) * 8;
    _Float16* b_dst[6];
#pragma unroll
    for (int k2 = 0; k2 < 6; ++k2) b_dst[k2] = Bs + (size_t)(k2 * 256 + wid * 64) * 8;

    int aoff[2][2], boff[2][3][2];
#pragma unroll
    for (int mf = 0; mf < 2; ++mf) {
        const int r = wm * 32 + mf * 16 + (lane & 15);
#pragma unroll
        for (int kk = 0; kk < 2; ++kk)
            aoff[mf][kk] = r * BK + (((kk * 4 + ku) ^ (r & 7)) * 8);
    }
#pragma unroll
    for (int jf = 0; jf < 2; ++jf)
#pragma unroll
        for (int g = 0; g < 3; ++g) {
            const int r = g * 64 + wj * 32 + jf * 16 + (lane & 15);
#pragma unroll
            for (int kk = 0; kk < 2; ++kk)
                boff[jf][g][kk] = r * BK + (((kk * 4 + ku) ^ (r & 7)) * 8);
        }

    for (int kt = 0; kt < 8; ++kt) {
        const int k0 = kt * BK;
#pragma unroll
        for (int k2 = 0; k2 < 2; ++k2) gload16(a_srcp[k2] + k0, a_dst[k2]);
#pragma unroll
        for (int k2 = 0; k2 < 6; ++k2) gload16(b_srcp[k2] + k0, b_dst[k2]);
        __syncthreads();
#pragma unroll
        for (int kk = 0; kk < 2; ++kk) {
            half8 af[2], bf[2][3];
#pragma unroll
            for (int mf = 0; mf < 2; ++mf) af[mf] = *(const half8*)(As + aoff[mf][kk]);
#pragma unroll
            for (int jf = 0; jf < 2; ++jf)
#pragma unroll
                for (int g = 0; g < 3; ++g) bf[jf][g] = *(const half8*)(Bs + boff[jf][g][kk]);
#pragma unroll
            for (int mf = 0; mf < 2; ++mf)
#pragma unroll
                for (int jf = 0; jf < 2; ++jf)
#pragma unroll
                    for (int g = 0; g < 3; ++g)
                        acc[mf][jf][g] = __builtin_amdgcn_mfma_f32_16x16x32_f16(
                            af[mf], bf[jf][g], acc[mf][jf][g], 0, 0, 0);
        }
        __syncthreads();
    }

    if (z == 0) {
        // fused gates0
#pragma unroll
        for (int mf = 0; mf < 2; ++mf)
#pragma unroll
            for (int jf = 0; jf < 2; ++jf) {
                const floatx4 gr = acc[mf][jf][0];
                const floatx4 gz = acc[mf][jf][1];
                const floatx4 gn = acc[mf][jf][2];
#pragma unroll
                for (int reg = 0; reg < 4; ++reg) {
                    const int m = m0 + wm * 32 + mf * 16 + (lane >> 4) * 4 + reg;
                    const int j = j0 + wj * 32 + jf * 16 + (lane & 15);
                    float gir = 0.f, giz = 0.f, gin = 0.f;
                    if (step > 0) {
                        const int tb = bits[m * SORB + step - 1];
                        gir = Wih0[j * 2 + tb];
                        giz = Wih0[(HID + j) * 2 + tb];
                        gin = Wih0[(2 * HID + j) * 2 + tb];
                    }
                    const float r  = sigmoidf_(gir + gr[reg]);
                    const float zz = sigmoidf_(giz + gz[reg]);
                    const float n  = tanhf_(gin + r * gn[reg]);
                    const size_t idx = (size_t)m * HID + j;
                    const float h  = h0f[idx];
                    const float hn = (1.f - zz) * n + zz * h;
                    h0f[idx]   = hn;
                    h0h_n[idx] = (_Float16)hn;
                }
            }
    } else {
#pragma unroll
        for (int mf = 0; mf < 2; ++mf)
#pragma unroll
            for (int jf = 0; jf < 2; ++jf)
#pragma unroll
                for (int g = 0; g < 3; ++g)
#pragma unroll
                    for (int reg = 0; reg < 4; ++reg) {
                        const int m = m0 + wm * 32 + mf * 16 + (lane >> 4) * 4 + reg;
                        const int j = j0 + wj * 32 + jf * 16 + (lane & 15);
                        gB[(size_t)m * N3H + g * HID + j] = (_Float16)acc[mf][jf][g][reg];
                    }
        // fused head(step-1): 512 z1-blocks x 8 rows (2 rows/wave)
        if (step > 0) {
            const int t = blockIdx.y * 8 + blockIdx.x;   // [0,512)
#pragma unroll
            for (int rr = 0; rr < 2; ++rr) {
                const int m = t * 8 + wid * 2 + rr;
                head_row(h1h_c, m, Wamp, bamp, Wph, bph, bits,
                         amp, phase, nup, ndn, out, step - 1, lane);
            }
        }
    }
}

// ================= step2: gi1 GEMM + fused gates1 (R11 form, unchanged) =================
__global__ __launch_bounds__(256) void step2_kernel(
    const _Float16* __restrict__ h0h_n, const _Float16* __restrict__ wi1,
    const _Float16* __restrict__ gB,
    float* __restrict__ h1f, _Float16* __restrict__ h1h_n)
{
    const int j0 = blockIdx.x * 64;
    const int m0 = blockIdx.y * 64;

    __shared__ __align__(16) _Float16 As[64 * BK];
    __shared__ __align__(16) _Float16 Bs[192 * BK];

    const int tid  = threadIdx.x;
    const int lane = tid & 63;
    const int wid  = tid >> 6;
    const int wm   = wid >> 1, wj = wid & 1;
    const int ku   = lane >> 4;

    floatx4 acc[2][2][3];
    const floatx4 z4 = {0.f, 0.f, 0.f, 0.f};
#pragma unroll
    for (int a = 0; a < 2; ++a)
#pragma unroll
        for (int b = 0; b < 2; ++b)
#pragma unroll
            for (int g = 0; g < 3; ++g) acc[a][b][g] = z4;

    const _Float16* a_srcp[2];
#pragma unroll
    for (int k2 = 0; k2 < 2; ++k2) {
        const int p = tid + k2 * 256, row = p >> 3, c = (p & 7) ^ (row & 7);
        a_srcp[k2] = h0h_n + (size_t)(m0 + row) * KD + c * 8;
    }
    const _Float16* b_srcp[6];
#pragma unroll
    for (int k2 = 0; k2 < 6; ++k2) {
        const int p = tid + k2 * 256, row = p >> 3, c = (p & 7) ^ (row & 7);
        const int grow = (row >> 6) * HID + j0 + (row & 63);
        b_srcp[k2] = wi1 + (size_t)grow * KD + c * 8;
    }
    _Float16* a_dst[2];
#pragma unroll
    for (int k2 = 0; k2 < 2; ++k2) a_dst[k2] = As + (size_t)(k2 * 256 + wid * 64) * 8;
    _Float16* b_dst[6];
#pragma unroll
    for (int k2 = 0; k2 < 6; ++k2) b_dst[k2] = Bs + (size_t)(k2 * 256 + wid * 64) * 8;

    int aoff[2][2], boff[2][3][2];
#pragma unroll
    for (int mf = 0; mf < 2; ++mf) {
        const int r = wm * 32 + mf * 16 + (lane & 15);
#pragma unroll
        for (int kk = 0; kk < 2; ++kk)
            aoff[mf][kk] = r * BK + (((kk * 4 + ku) ^ (r & 7)) * 8);
    }
#pragma unroll
    for (int jf = 0; jf < 2; ++jf)
#pragma unroll
        for (int g = 0; g < 3; ++g) {
            const int r = g * 64 + wj * 32 + jf * 16 + (lane & 15);
#pragma unroll
            for (int kk = 0; kk < 2; ++kk)
                boff[jf][g][kk] = r * BK + (((kk * 4 + ku) ^ (r & 7)) * 8);
        }

    for (int kt = 0; kt < 8; ++kt) {
        const int k0 = kt * BK;
#pragma unroll
        for (int k2 = 0; k2 < 2; ++k2) gload16(a_srcp[k2] + k0, a_dst[k2]);
#pragma unroll
        for (int k2 = 0; k2 < 6; ++k2) gload16(b_srcp[k2] + k0, b_dst[k2]);
        __syncthreads();
#pragma unroll
        for (int kk = 0; kk < 2; ++kk) {
            half8 af[2], bf[2][3];
#pragma unroll
            for (int mf = 0; mf < 2; ++mf) af[mf] = *(const half8*)(As + aoff[mf][kk]);
#pragma unroll
            for (int jf = 0; jf < 2; ++jf)
#pragma unroll
                for (int g = 0; g < 3; ++g) bf[jf][g] = *(const half8*)(Bs + boff[jf][g][kk]);
#pragma unroll
            for (int mf = 0; mf < 2; ++mf)
#pragma unroll
                for (int jf = 0; jf < 2; ++jf)
#pragma unroll
                    for (int g = 0; g < 3; ++g)
                        acc[mf][jf][g] = __builtin_amdgcn_mfma_f32_16x16x32_f16(
                            af[mf], bf[jf][g], acc[mf][jf][g], 0, 0, 0);
        }
        __syncthreads();
    }

    // fused gates1
#pragma unroll
    for (int mf = 0; mf < 2; ++mf)
#pragma unroll
        for (int jf = 0; jf < 2; ++jf) {
            const floatx4 gr = acc[mf][jf][0];
            const floatx4 gz = acc[mf][jf][1];
            const floatx4 gn = acc[mf][jf][2];
#pragma unroll
            for (int reg = 0; reg < 4; ++reg) {
                const int m = m0 + wm * 32 + mf * 16 + (lane >> 4) * 4 + reg;
                const int j = j0 + wj * 32 + jf * 16 + (lane & 15);
                const size_t gbase = (size_t)m * N3H;
                const float ghr = (float)gB[gbase + j];
                const float ghz = (float)gB[gbase + HID + j];
                const float ghn = (float)gB[gbase + 2 * HID + j];
                const float r  = sigmoidf_(gr[reg] + ghr);
                const float zz = sigmoidf_(gz[reg] + ghz);
                const float n  = tanhf_(gn[reg] + r * ghn);
                const size_t idx = (size_t)m * HID + j;
                const float h  = h1f[idx];
                const float hn = (1.f - zz) * n + zz * h;
                h1f[idx]   = hn;
                h1h_n[idx] = (_Float16)hn;
            }
        }
}

// ================= final head (step 63) =================
__global__ __launch_bounds__(256) void head_kernel(
    const _Float16* __restrict__ h1h_n,
    const float* __restrict__ Wamp, const float* __restrict__ bamp,
    const float* __restrict__ Wph,  const float* __restrict__ bph,
    const int* __restrict__ bits,
    float* __restrict__ amp, float* __restrict__ phase,
    int* __restrict__ nup, int* __restrict__ ndn,
    float* __restrict__ out, int step)
{
    const int lane = threadIdx.x & 63;
    const int m    = blockIdx.x * 4 + (threadIdx.x >> 6);
    head_row(h1h_n, m, Wamp, bamp, Wph, bph, bits, amp, phase, nup, ndn, out, step, lane);
}

extern "C" void kernel_launch(void* const* d_in, const int* in_sizes, int n_in,
                              void* d_out, int out_size, void* d_ws, size_t ws_size,
                              hipStream_t stream) {
    const int*   bits = (const int*)d_in[0];
    const float* Wih0 = (const float*)d_in[1];
    const float* Whh0 = (const float*)d_in[2];
    const float* Wih1 = (const float*)d_in[3];
    const float* Whh1 = (const float*)d_in[4];
    const float* Wamp = (const float*)d_in[5];
    const float* bamp = (const float*)d_in[6];
    const float* Wph  = (const float*)d_in[7];
    const float* bph  = (const float*)d_in[8];
    float* out = (float*)d_out;

    char* ws = (char*)d_ws;
    size_t off = 0;
    auto alloc = [&](size_t bytes) {
        void* p = ws + off;
        off = (off + bytes + 255) & ~(size_t)255;
        return p;
    };
    _Float16* wh0 = (_Float16*)alloc((size_t)N3H * KD * 2);
    _Float16* wi1 = (_Float16*)alloc((size_t)N3H * KD * 2);
    _Float16* wh1 = (_Float16*)alloc((size_t)N3H * KD * 2);
    float*    h0f = (float*)alloc((size_t)BATCH * HID * 4);
    float*    h1f = (float*)alloc((size_t)BATCH * HID * 4);
    _Float16* h0hA = (_Float16*)alloc((size_t)BATCH * HID * 2);
    _Float16* h0hB = (_Float16*)alloc((size_t)BATCH * HID * 2);
    _Float16* h1hA = (_Float16*)alloc((size_t)BATCH * HID * 2);
    _Float16* h1hB = (_Float16*)alloc((size_t)BATCH * HID * 2);
    _Float16* gB  = (_Float16*)alloc((size_t)BATCH * N3H * 2);
    float*    amp   = (float*)alloc((size_t)BATCH * 4);
    float*    phase = (float*)alloc((size_t)BATCH * 4);
    int*      nup   = (int*)alloc((size_t)BATCH * 4);
    int*      ndn   = (int*)alloc((size_t)BATCH * 4);

    _Float16* h0h[2] = {h0hA, h0hB};
    _Float16* h1h[2] = {h1hA, h1hB};

    hipMemsetAsync(h0f, 0, (size_t)BATCH * HID * 4, stream);
    hipMemsetAsync(h1f, 0, (size_t)BATCH * HID * 4, stream);
    hipMemsetAsync(h0hA, 0, (size_t)BATCH * HID * 2, stream);
    hipMemsetAsync(h1hA, 0, (size_t)BATCH * HID * 2, stream);
    convw_kernel<<<(N3H * KD + 255) / 256, 256, 0, stream>>>(Whh0, Wih1, Whh1, wh0, wi1, wh1);
    init_kernel<<<BATCH / 256, 256, 0, stream>>>(amp, phase, nup, ndn);

    for (int s = 0; s < SORB; ++s) {
        const int cur = s & 1, nxt = cur ^ 1;
        step1_kernel<<<dim3(8, 64, 2), 256, 0, stream>>>(
            h0h[cur], h1h[cur], wh0, wh1, Wih0, bits, h0f, h0h[nxt], gB, s,
            Wamp, bamp, Wph, bph, amp, phase, nup, ndn, out);
        step2_kernel<<<dim3(8, 64), 256, 0, stream>>>(
            h0h[nxt], wi1, gB, h1f, h1h[nxt]);
    }
    head_kernel<<<BATCH / 4, 256, 0, stream>>>(
        h1h[0], Wamp, bamp, Wph, bph, bits, amp, phase, nup, ndn, out, SORB - 1);
}

// Round 16
// 3060.628 us; speedup vs baseline: 4.0485x; 1.1109x over previous
//
#include <hip/hip_runtime.h>
#include <hip/hip_bf16.h>

#define SORB  64
#define HID   512
#define BATCH 4096
#define N3H   1536
#define KD    512
#define BK    64
#define PI_F  3.14159265358979f

typedef _Float16 half8 __attribute__((ext_vector_type(8)));
typedef float    floatx4 __attribute__((ext_vector_type(4)));

__device__ __forceinline__ void gload16(const void* g, void* l) {
    __builtin_amdgcn_global_load_lds(
        (const __attribute__((address_space(1))) void*)g,
        (__attribute__((address_space(3))) void*)l, 16, 0, 0);
}

__device__ __forceinline__ float sigmoidf_(float x) { return 1.f / (1.f + __expf(-x)); }
__device__ __forceinline__ float tanhf_(float x) {
    x = fminf(fmaxf(x, -15.f), 15.f);
    const float e2 = __expf(2.f * x);
    return (e2 - 1.f) / (e2 + 1.f);
}

__global__ __launch_bounds__(256) void convw_kernel(
    const float* __restrict__ w0, const float* __restrict__ w1, const float* __restrict__ w2,
    _Float16* __restrict__ o0, _Float16* __restrict__ o1, _Float16* __restrict__ o2)
{
    const int i = blockIdx.x * 256 + threadIdx.x;
    if (i < N3H * KD) {
        o0[i] = (_Float16)w0[i];
        o1[i] = (_Float16)w1[i];
        o2[i] = (_Float16)w2[i];
    }
}

__global__ __launch_bounds__(256) void init_kernel(
    float* __restrict__ amp, float* __restrict__ phase,
    int* __restrict__ nup, int* __restrict__ ndn)
{
    const int i = blockIdx.x * 256 + threadIdx.x;
    if (i < BATCH) { amp[i] = 1.f; phase[i] = 0.f; nup[i] = 0; ndn[i] = 0; }
}

// ================= step1: gh0 GEMM + fused gates0 (f16 h-state only) =================
// Grid (8,64), 256 thr = 4 waves (2m x 2j). BM=64, J=64 (B 192 rows), BK=64.
// R11's verified single-buffer K-loop with global_load_lds + XOR-swizzled source.
__global__ __launch_bounds__(256) void step1_kernel(
    const _Float16* __restrict__ h0h_c, const _Float16* __restrict__ wh0,
    const float* __restrict__ Wih0, const int* __restrict__ bits,
    _Float16* __restrict__ h0h_n, int step)
{
    const int j0 = blockIdx.x * 64;
    const int m0 = blockIdx.y * 64;

    __shared__ __align__(16) _Float16 As[64 * BK];    // 8 KB
    __shared__ __align__(16) _Float16 Bs[192 * BK];   // 24 KB

    const int tid  = threadIdx.x;
    const int lane = tid & 63;
    const int wid  = tid >> 6;
    const int wm   = wid >> 1, wj = wid & 1;
    const int ku   = lane >> 4;

    floatx4 acc[2][2][3];
    const floatx4 z4 = {0.f, 0.f, 0.f, 0.f};
#pragma unroll
    for (int a = 0; a < 2; ++a)
#pragma unroll
        for (int b = 0; b < 2; ++b)
#pragma unroll
            for (int g = 0; g < 3; ++g) acc[a][b][g] = z4;

    const _Float16* a_srcp[2];
#pragma unroll
    for (int k2 = 0; k2 < 2; ++k2) {
        const int p = tid + k2 * 256, row = p >> 3, c = (p & 7) ^ (row & 7);
        a_srcp[k2] = h0h_c + (size_t)(m0 + row) * KD + c * 8;
    }
    const _Float16* b_srcp[6];
#pragma unroll
    for (int k2 = 0; k2 < 6; ++k2) {
        const int p = tid + k2 * 256, row = p >> 3, c = (p & 7) ^ (row & 7);
        const int grow = (row >> 6) * HID + j0 + (row & 63);
        b_srcp[k2] = wh0 + (size_t)grow * KD + c * 8;
    }
    _Float16* a_dst[2];
#pragma unroll
    for (int k2 = 0; k2 < 2; ++k2) a_dst[k2] = As + (size_t)(k2 * 256 + wid * 64) * 8;
    _Float16* b_dst[6];
#pragma unroll
    for (int k2 = 0; k2 < 6; ++k2) b_dst[k2] = Bs + (size_t)(k2 * 256 + wid * 64) * 8;

    int aoff[2][2], boff[2][3][2];
#pragma unroll
    for (int mf = 0; mf < 2; ++mf) {
        const int r = wm * 32 + mf * 16 + (lane & 15);
#pragma unroll
        for (int kk = 0; kk < 2; ++kk)
            aoff[mf][kk] = r * BK + (((kk * 4 + ku) ^ (r & 7)) * 8);
    }
#pragma unroll
    for (int jf = 0; jf < 2; ++jf)
#pragma unroll
        for (int g = 0; g < 3; ++g) {
            const int r = g * 64 + wj * 32 + jf * 16 + (lane & 15);
#pragma unroll
            for (int kk = 0; kk < 2; ++kk)
                boff[jf][g][kk] = r * BK + (((kk * 4 + ku) ^ (r & 7)) * 8);
        }

    for (int kt = 0; kt < 8; ++kt) {
        const int k0 = kt * BK;
#pragma unroll
        for (int k2 = 0; k2 < 2; ++k2) gload16(a_srcp[k2] + k0, a_dst[k2]);
#pragma unroll
        for (int k2 = 0; k2 < 6; ++k2) gload16(b_srcp[k2] + k0, b_dst[k2]);
        __syncthreads();
#pragma unroll
        for (int kk = 0; kk < 2; ++kk) {
            half8 af[2], bf[2][3];
#pragma unroll
            for (int mf = 0; mf < 2; ++mf) af[mf] = *(const half8*)(As + aoff[mf][kk]);
#pragma unroll
            for (int jf = 0; jf < 2; ++jf)
#pragma unroll
                for (int g = 0; g < 3; ++g) bf[jf][g] = *(const half8*)(Bs + boff[jf][g][kk]);
#pragma unroll
            for (int mf = 0; mf < 2; ++mf)
#pragma unroll
                for (int jf = 0; jf < 2; ++jf)
#pragma unroll
                    for (int g = 0; g < 3; ++g)
                        acc[mf][jf][g] = __builtin_amdgcn_mfma_f32_16x16x32_f16(
                            af[mf], bf[jf][g], acc[mf][jf][g], 0, 0, 0);
        }
        __syncthreads();
    }

    // fused gates0: h0n = (1-z)*n + z*h0   (h-state f16-only)
#pragma unroll
    for (int mf = 0; mf < 2; ++mf)
#pragma unroll
        for (int jf = 0; jf < 2; ++jf) {
            const floatx4 gr = acc[mf][jf][0];
            const floatx4 gz = acc[mf][jf][1];
            const floatx4 gn = acc[mf][jf][2];
#pragma unroll
            for (int reg = 0; reg < 4; ++reg) {
                const int m = m0 + wm * 32 + mf * 16 + (lane >> 4) * 4 + reg;
                const int j = j0 + wj * 32 + jf * 16 + (lane & 15);
                float gir = 0.f, giz = 0.f, gin = 0.f;
                if (step > 0) {
                    const int tb = bits[m * SORB + step - 1];
                    gir = Wih0[j * 2 + tb];
                    giz = Wih0[(HID + j) * 2 + tb];
                    gin = Wih0[(2 * HID + j) * 2 + tb];
                }
                const float r  = sigmoidf_(gir + gr[reg]);
                const float zz = sigmoidf_(giz + gz[reg]);
                const float n  = tanhf_(gin + r * gn[reg]);
                const size_t idx = (size_t)m * HID + j;
                const float h  = (float)h0h_c[idx];
                h0h_n[idx] = (_Float16)((1.f - zz) * n + zz * h);
            }
        }
}

// ================= step2: dual-K GEMM (gi1 + gh1) + fused gates1 =================
// acc = h0n @ wi1^T + h1c @ wh1^T  (two 8-kt passes into the same accumulators).
__global__ __launch_bounds__(256) void step2_kernel(
    const _Float16* __restrict__ h0h_n, const _Float16* __restrict__ h1h_c,
    const _Float16* __restrict__ wi1,   const _Float16* __restrict__ wh1,
    _Float16* __restrict__ h1h_n)
{
    const int j0 = blockIdx.x * 64;
    const int m0 = blockIdx.y * 64;

    __shared__ __align__(16) _Float16 As[64 * BK];
    __shared__ __align__(16) _Float16 Bs[192 * BK];

    const int tid  = threadIdx.x;
    const int lane = tid & 63;
    const int wid  = tid >> 6;
    const int wm   = wid >> 1, wj = wid & 1;
    const int ku   = lane >> 4;

    floatx4 acc[2][2][3];
    const floatx4 z4 = {0.f, 0.f, 0.f, 0.f};
#pragma unroll
    for (int a = 0; a < 2; ++a)
#pragma unroll
        for (int b = 0; b < 2; ++b)
#pragma unroll
            for (int g = 0; g < 3; ++g) acc[a][b][g] = z4;

    _Float16* a_dst[2];
#pragma unroll
    for (int k2 = 0; k2 < 2; ++k2) a_dst[k2] = As + (size_t)(k2 * 256 + wid * 64) * 8;
    _Float16* b_dst[6];
#pragma unroll
    for (int k2 = 0; k2 < 6; ++k2) b_dst[k2] = Bs + (size_t)(k2 * 256 + wid * 64) * 8;

    int aoff[2][2], boff[2][3][2];
#pragma unroll
    for (int mf = 0; mf < 2; ++mf) {
        const int r = wm * 32 + mf * 16 + (lane & 15);
#pragma unroll
        for (int kk = 0; kk < 2; ++kk)
            aoff[mf][kk] = r * BK + (((kk * 4 + ku) ^ (r & 7)) * 8);
    }
#pragma unroll
    for (int jf = 0; jf < 2; ++jf)
#pragma unroll
        for (int g = 0; g < 3; ++g) {
            const int r = g * 64 + wj * 32 + jf * 16 + (lane & 15);
#pragma unroll
            for (int kk = 0; kk < 2; ++kk)
                boff[jf][g][kk] = r * BK + (((kk * 4 + ku) ^ (r & 7)) * 8);
        }

#pragma unroll 1
    for (int half = 0; half < 2; ++half) {
        const _Float16* Aop = half ? h1h_c : h0h_n;
        const _Float16* Wop = half ? wh1  : wi1;
        const _Float16* a_srcp[2];
#pragma unroll
        for (int k2 = 0; k2 < 2; ++k2) {
            const int p = tid + k2 * 256, row = p >> 3, c = (p & 7) ^ (row & 7);
            a_srcp[k2] = Aop + (size_t)(m0 + row) * KD + c * 8;
        }
        const _Float16* b_srcp[6];
#pragma unroll
        for (int k2 = 0; k2 < 6; ++k2) {
            const int p = tid + k2 * 256, row = p >> 3, c = (p & 7) ^ (row & 7);
            const int grow = (row >> 6) * HID + j0 + (row & 63);
            b_srcp[k2] = Wop + (size_t)grow * KD + c * 8;
        }

        for (int kt = 0; kt < 8; ++kt) {
            const int k0 = kt * BK;
#pragma unroll
            for (int k2 = 0; k2 < 2; ++k2) gload16(a_srcp[k2] + k0, a_dst[k2]);
#pragma unroll
            for (int k2 = 0; k2 < 6; ++k2) gload16(b_srcp[k2] + k0, b_dst[k2]);
            __syncthreads();
#pragma unroll
            for (int kk = 0; kk < 2; ++kk) {
                half8 af[2], bf[2][3];
#pragma unroll
                for (int mf = 0; mf < 2; ++mf) af[mf] = *(const half8*)(As + aoff[mf][kk]);
#pragma unroll
                for (int jf = 0; jf < 2; ++jf)
#pragma unroll
                    for (int g = 0; g < 3; ++g) bf[jf][g] = *(const half8*)(Bs + boff[jf][g][kk]);
#pragma unroll
                for (int mf = 0; mf < 2; ++mf)
#pragma unroll
                    for (int jf = 0; jf < 2; ++jf)
#pragma unroll
                        for (int g = 0; g < 3; ++g)
                            acc[mf][jf][g] = __builtin_amdgcn_mfma_f32_16x16x32_f16(
                                af[mf], bf[jf][g], acc[mf][jf][g], 0, 0, 0);
            }
            __syncthreads();
        }
    }

    // fused gates1 (h-state f16-only)
#pragma unroll
    for (int mf = 0; mf < 2; ++mf)
#pragma unroll
        for (int jf = 0; jf < 2; ++jf) {
            const floatx4 gr = acc[mf][jf][0];
            const floatx4 gz = acc[mf][jf][1];
            const floatx4 gn = acc[mf][jf][2];
#pragma unroll
            for (int reg = 0; reg < 4; ++reg) {
                const int m = m0 + wm * 32 + mf * 16 + (lane >> 4) * 4 + reg;
                const int j = j0 + wj * 32 + jf * 16 + (lane & 15);
                const float r  = sigmoidf_(gr[reg]);   // placeholder, replaced below
                (void)r;
                // NOTE: gi and gh are summed inside acc already (dual-K), but the GRU
                // gate n needs r * gh_n separately -- see derivation below.
            }
        }
    // --- correct gates1: we need gh_n separately for n = tanh(gi_n + r*gh_n). ---
    // acc currently holds gi+gh summed, which is WRONG for the n-gate.  To keep
    // correctness we recompute: store gh contribution separately would need 2x acc.
    // Instead: r,z gates use summed acc (correct: sigmoid(gi+gh)); for n we must
    // not use summed form.  Therefore this kernel keeps a SECOND accumulator for
    // the n-gate's gh part only. (Handled via accn below.)
}

// The dual-K fusion above breaks the n-gate (needs r*gh_n, not gi_n+gh_n).
// Fall back: keep gB for the n-gate only (1/3 the traffic of full gB).
// ---- replacement step2 with n-gate gh accumulator ----
__global__ __launch_bounds__(256) void step2b_kernel(
    const _Float16* __restrict__ h0h_n, const _Float16* __restrict__ h1h_c,
    const _Float16* __restrict__ wi1,   const _Float16* __restrict__ wh1,
    _Float16* __restrict__ h1h_n)
{
    const int j0 = blockIdx.x * 64;
    const int m0 = blockIdx.y * 64;

    __shared__ __align__(16) _Float16 As[64 * BK];
    __shared__ __align__(16) _Float16 Bs[192 * BK];

    const int tid  = threadIdx.x;
    const int lane = tid & 63;
    const int wid  = tid >> 6;
    const int wm   = wid >> 1, wj = wid & 1;
    const int ku   = lane >> 4;

    floatx4 acc[2][2][3];    // gi sums (half 0) then r,z add gh; n kept separate
    floatx4 accn[2][2];      // gh_n (half 1, gate 2) separate
    const floatx4 z4 = {0.f, 0.f, 0.f, 0.f};
#pragma unroll
    for (int a = 0; a < 2; ++a)
#pragma unroll
        for (int b = 0; b < 2; ++b) {
#pragma unroll
            for (int g = 0; g < 3; ++g) acc[a][b][g] = z4;
            accn[a][b] = z4;
        }

    _Float16* a_dst[2];
#pragma unroll
    for (int k2 = 0; k2 < 2; ++k2) a_dst[k2] = As + (size_t)(k2 * 256 + wid * 64) * 8;
    _Float16* b_dst[6];
#pragma unroll
    for (int k2 = 0; k2 < 6; ++k2) b_dst[k2] = Bs + (size_t)(k2 * 256 + wid * 64) * 8;

    int aoff[2][2], boff[2][3][2];
#pragma unroll
    for (int mf = 0; mf < 2; ++mf) {
        const int r = wm * 32 + mf * 16 + (lane & 15);
#pragma unroll
        for (int kk = 0; kk < 2; ++kk)
            aoff[mf][kk] = r * BK + (((kk * 4 + ku) ^ (r & 7)) * 8);
    }
#pragma unroll
    for (int jf = 0; jf < 2; ++jf)
#pragma unroll
        for (int g = 0; g < 3; ++g) {
            const int r = g * 64 + wj * 32 + jf * 16 + (lane & 15);
#pragma unroll
            for (int kk = 0; kk < 2; ++kk)
                boff[jf][g][kk] = r * BK + (((kk * 4 + ku) ^ (r & 7)) * 8);
        }

#pragma unroll 1
    for (int half = 0; half < 2; ++half) {
        const _Float16* Aop = half ? h1h_c : h0h_n;
        const _Float16* Wop = half ? wh1  : wi1;
        const _Float16* a_srcp[2];
#pragma unroll
        for (int k2 = 0; k2 < 2; ++k2) {
            const int p = tid + k2 * 256, row = p >> 3, c = (p & 7) ^ (row & 7);
            a_srcp[k2] = Aop + (size_t)(m0 + row) * KD + c * 8;
        }
        const _Float16* b_srcp[6];
#pragma unroll
        for (int k2 = 0; k2 < 6; ++k2) {
            const int p = tid + k2 * 256, row = p >> 3, c = (p & 7) ^ (row & 7);
            const int grow = (row >> 6) * HID + j0 + (row & 63);
            b_srcp[k2] = Wop + (size_t)grow * KD + c * 8;
        }

        for (int kt = 0; kt < 8; ++kt) {
            const int k0 = kt * BK;
#pragma unroll
            for (int k2 = 0; k2 < 2; ++k2) gload16(a_srcp[k2] + k0, a_dst[k2]);
#pragma unroll
            for (int k2 = 0; k2 < 6; ++k2) gload16(b_srcp[k2] + k0, b_dst[k2]);
            __syncthreads();
#pragma unroll
            for (int kk = 0; kk < 2; ++kk) {
                half8 af[2], bf[2][3];
#pragma unroll
                for (int mf = 0; mf < 2; ++mf) af[mf] = *(const half8*)(As + aoff[mf][kk]);
#pragma unroll
                for (int jf = 0; jf < 2; ++jf)
#pragma unroll
                    for (int g = 0; g < 3; ++g) bf[jf][g] = *(const half8*)(Bs + boff[jf][g][kk]);
#pragma unroll
                for (int mf = 0; mf < 2; ++mf)
#pragma unroll
                    for (int jf = 0; jf < 2; ++jf) {
                        acc[mf][jf][0] = __builtin_amdgcn_mfma_f32_16x16x32_f16(
                            af[mf], bf[jf][0], acc[mf][jf][0], 0, 0, 0);
                        acc[mf][jf][1] = __builtin_amdgcn_mfma_f32_16x16x32_f16(
                            af[mf], bf[jf][1], acc[mf][jf][1], 0, 0, 0);
                        if (half == 0)
                            acc[mf][jf][2] = __builtin_amdgcn_mfma_f32_16x16x32_f16(
                                af[mf], bf[jf][2], acc[mf][jf][2], 0, 0, 0);
                        else
                            accn[mf][jf] = __builtin_amdgcn_mfma_f32_16x16x32_f16(
                                af[mf], bf[jf][2], accn[mf][jf], 0, 0, 0);
                    }
            }
            __syncthreads();
        }
    }

    // fused gates1: r=sig(gi_r+gh_r), z=sig(gi_z+gh_z), n=tanh(gi_n + r*gh_n)
#pragma unroll
    for (int mf = 0; mf < 2; ++mf)
#pragma unroll
        for (int jf = 0; jf < 2; ++jf) {
            const floatx4 grz = acc[mf][jf][0];
            const floatx4 gzz = acc[mf][jf][1];
            const floatx4 gin = acc[mf][jf][2];
            const floatx4 ghn = accn[mf][jf];
#pragma unroll
            for (int reg = 0; reg < 4; ++reg) {
                const int m = m0 + wm * 32 + mf * 16 + (lane >> 4) * 4 + reg;
                const int j = j0 + wj * 32 + jf * 16 + (lane & 15);
                const float r  = sigmoidf_(grz[reg]);
                const float zz = sigmoidf_(gzz[reg]);
                const float n  = tanhf_(gin[reg] + r * ghn[reg]);
                const size_t idx = (size_t)m * HID + j;
                const float h  = (float)h1h_c[idx];
                h1h_n[idx] = (_Float16)((1.f - zz) * n + zz * h);
            }
        }
}

// ================= head =================
__global__ __launch_bounds__(256) void head_kernel(
    const _Float16* __restrict__ h1h_n,
    const float* __restrict__ Wamp, const float* __restrict__ bamp,
    const float* __restrict__ Wph,  const float* __restrict__ bph,
    const int* __restrict__ bits,
    float* __restrict__ amp, float* __restrict__ phase,
    int* __restrict__ nup, int* __restrict__ ndn,
    float* __restrict__ out, int step)
{
    const int lane = threadIdx.x & 63;
    const int m    = blockIdx.x * 4 + (threadIdx.x >> 6);
    const half8 hv = *(const half8*)(h1h_n + (size_t)m * HID + lane * 8);
    float d0 = 0.f, d1 = 0.f, d2 = 0.f, d3 = 0.f;
#pragma unroll
    for (int e = 0; e < 8; ++e) {
        const int j = lane * 8 + e;
        const float hn = (float)hv[e];
        d0 += hn * Wamp[j];       d1 += hn * Wamp[HID + j];
        d2 += hn * Wph[j];        d3 += hn * Wph[HID + j];
    }
#pragma unroll
    for (int off = 1; off < 64; off <<= 1) {
        d0 += __shfl_xor(d0, off); d1 += __shfl_xor(d1, off);
        d2 += __shfl_xor(d2, off); d3 += __shfl_xor(d3, off);
    }
    if (lane == 0) {
        const float a0 = d0 + bamp[0];
        const float a1 = d1 + bamp[1];
        const float mx = fmaxf(a0, a1);
        const float e0 = __expf(a0 - mx), e1 = __expf(a1 - mx);
        const float inv = 1.f / (e0 + e1);
        float ya0 = sqrtf(e0 * inv), ya1 = sqrtf(e1 * inv);
        const float p0 = d2 + bph[0];
        const float p1 = d3 + bph[1];
        const float yp0 = PI_F * p0 / (1.f + fabsf(p0));
        const float yp1 = PI_F * p1 / (1.f + fabsf(p1));
        const int even = ((step & 1) == 0);
        const int cnt = even ? nup[m] : ndn[m];
        if (step >= 32) {  // MIN_I
            const int lower = (step >> 1) - 16;
            const float m0v = (cnt > lower) ? ya0 : 0.f;
            const float m1v = (cnt < 16) ? ya1 : 0.f;
            const float nrm = sqrtf(m0v * m0v + m1v * m1v + 1e-12f);
            ya0 = m0v / nrm; ya1 = m1v / nrm;
        }
        const int bi = bits[m * SORB + step];
        const float na = amp[m] * (bi ? ya1 : ya0);
        const float np = phase[m] + (bi ? yp1 : yp0);
        amp[m] = na; phase[m] = np;
        if (bi) { if (even) nup[m] = cnt + 1; else ndn[m] = cnt + 1; }
        if (step == SORB - 1) {
            out[m * 2 + 0] = na;
            out[m * 2 + 1] = np;
        }
    }
}

extern "C" void kernel_launch(void* const* d_in, const int* in_sizes, int n_in,
                              void* d_out, int out_size, void* d_ws, size_t ws_size,
                              hipStream_t stream) {
    const int*   bits = (const int*)d_in[0];
    const float* Wih0 = (const float*)d_in[1];
    const float* Whh0 = (const float*)d_in[2];
    const float* Wih1 = (const float*)d_in[3];
    const float* Whh1 = (const float*)d_in[4];
    const float* Wamp = (const float*)d_in[5];
    const float* bamp = (const float*)d_in[6];
    const float* Wph  = (const float*)d_in[7];
    const float* bph  = (const float*)d_in[8];
    float* out = (float*)d_out;

    char* ws = (char*)d_ws;
    size_t off = 0;
    auto alloc = [&](size_t bytes) {
        void* p = ws + off;
        off = (off + bytes + 255) & ~(size_t)255;
        return p;
    };
    _Float16* wh0 = (_Float16*)alloc((size_t)N3H * KD * 2);
    _Float16* wi1 = (_Float16*)alloc((size_t)N3H * KD * 2);
    _Float16* wh1 = (_Float16*)alloc((size_t)N3H * KD * 2);
    _Float16* h0hA = (_Float16*)alloc((size_t)BATCH * HID * 2);
    _Float16* h0hB = (_Float16*)alloc((size_t)BATCH * HID * 2);
    _Float16* h1hA = (_Float16*)alloc((size_t)BATCH * HID * 2);
    _Float16* h1hB = (_Float16*)alloc((size_t)BATCH * HID * 2);
    float*    amp   = (float*)alloc((size_t)BATCH * 4);
    float*    phase = (float*)alloc((size_t)BATCH * 4);
    int*      nup   = (int*)alloc((size_t)BATCH * 4);
    int*      ndn   = (int*)alloc((size_t)BATCH * 4);

    _Float16* h0h[2] = {h0hA, h0hB};
    _Float16* h1h[2] = {h1hA, h1hB};

    hipMemsetAsync(h0hA, 0, (size_t)BATCH * HID * 2, stream);
    hipMemsetAsync(h1hA, 0, (size_t)BATCH * HID * 2, stream);
    convw_kernel<<<(N3H * KD + 255) / 256, 256, 0, stream>>>(Whh0, Wih1, Whh1, wh0, wi1, wh1);
    init_kernel<<<BATCH / 256, 256, 0, stream>>>(amp, phase, nup, ndn);

    for (int s = 0; s < SORB; ++s) {
        const int cur = s & 1, nxt = cur ^ 1;
        step1_kernel<<<dim3(8, 64), 256, 0, stream>>>(
            h0h[cur], wh0, Wih0, bits, h0h[nxt], s);
        step2b_kernel<<<dim3(8, 64), 256, 0, stream>>>(
            h0h[nxt], h1h[cur], wi1, wh1, h1h[nxt]);
        head_kernel<<<BATCH / 4, 256, 0, stream>>>(
            h1h[nxt], Wamp, bamp, Wph, bph, bits, amp, phase, nup, ndn, out, s);
    }
}